// Round 1
// baseline (376.606 us; speedup 1.0000x reference)
//
#include <hip/hip_runtime.h>
#include <math.h>

// Problem constants (fixed-shape harness: B=4, L=1024, U=256, H=8, dh=32, td=8)
#define B_DIM 4
#define L_DIM 1024
#define H_DIM 8
#define D_DIM 32
#define TD 8
#define TQ 16
#define TK 32
#define SCALE 0.17677669529663687f          // 1/sqrt(32)
#define TWO_PI_D 6.283185307179586476925287
#define INV_TWO_PI_D 0.15915494309189533577

// ---------------------------------------------------------------------------
// Kernel 1: per-position time features.
// For each (b,i): three 1->8->8 relu MLPs (period/sigma/basis), computed in
// fp64 (cheap: 4096 positions). Store qpq = 2*pi*period*t as DOUBLE (cos of
// ~1e5-magnitude args is ulp-sensitive; fp64 keeps us accurate), sigma+1e-6
// and basis as float.
// ---------------------------------------------------------------------------
__device__ __forceinline__ void mlp8(double t, const float* __restrict__ W1,
                                     const float* __restrict__ b1,
                                     const float* __restrict__ W2,
                                     const float* __restrict__ b2,
                                     double* o) {
  double h[TD];
#pragma unroll
  for (int d = 0; d < TD; ++d) {
    double v = t * (double)W1[d] + (double)b1[d];
    h[d] = v > 0.0 ? v : 0.0;
  }
#pragma unroll
  for (int e = 0; e < TD; ++e) {
    double v = (double)b2[e];
#pragma unroll
    for (int d = 0; d < TD; ++d) v += h[d] * (double)W2[d * TD + e];
    o[e] = v > 0.0 ? v : 0.0;
  }
}

__global__ __launch_bounds__(256) void time_feat_kernel(
    const float* __restrict__ t_in,
    const float* __restrict__ pW1, const float* __restrict__ pb1,
    const float* __restrict__ pW2, const float* __restrict__ pb2,
    const float* __restrict__ sW1, const float* __restrict__ sb1,
    const float* __restrict__ sW2, const float* __restrict__ sb2,
    const float* __restrict__ bW1, const float* __restrict__ bb1,
    const float* __restrict__ bW2, const float* __restrict__ bb2,
    double* __restrict__ qpq, float* __restrict__ sg, float* __restrict__ bs,
    int total) {
  int i = blockIdx.x * blockDim.x + threadIdx.x;
  if (i >= total) return;
  double t = (double)t_in[i];
  double o[TD];
  mlp8(t, pW1, pb1, pW2, pb2, o);
#pragma unroll
  for (int d = 0; d < TD; ++d) qpq[(size_t)i * TD + d] = TWO_PI_D * o[d] * t;
  mlp8(t, sW1, sb1, sW2, sb2, o);
#pragma unroll
  for (int d = 0; d < TD; ++d) sg[(size_t)i * TD + d] = (float)(o[d] + 1e-6);
  mlp8(t, bW1, bb1, bW2, bb2, o);
#pragma unroll
  for (int d = 0; d < TD; ++d) bs[(size_t)i * TD + d] = (float)o[d];
}

// ---------------------------------------------------------------------------
// Kernel 2: X[4096,256] @ W[256,256] -> out in [B][H][L][dh] layout.
// BM=64 BN=64 BK=16, 256 threads, 4x4 microtile, fp32 vector.
// ---------------------------------------------------------------------------
__global__ __launch_bounds__(256) void gemm_qkv(
    const float* __restrict__ X, const float* __restrict__ W,
    float* __restrict__ out) {
  __shared__ float As[16][64];
  __shared__ float Bs[16][64];
  const int tid = threadIdx.x;
  const int m0 = (blockIdx.x >> 2) << 6;
  const int n0 = (blockIdx.x & 3) << 6;
  const int tx = tid & 15;   // n
  const int ty = tid >> 4;   // m
  const int ar = tid >> 2;          // A row 0..63
  const int ak = (tid & 3) << 2;    // A k-offset 0,4,8,12
  const int brk = tid >> 4;         // B k-row 0..15
  const int bn = (tid & 15) << 2;   // B n-offset
  float acc[4][4] = {{0.f}};
  for (int k0 = 0; k0 < 256; k0 += 16) {
    float4 av = *(const float4*)&X[(size_t)(m0 + ar) * 256 + k0 + ak];
    *(float4*)&Bs[brk][bn] = *(const float4*)&W[(size_t)(k0 + brk) * 256 + n0 + bn];
    As[ak + 0][ar] = av.x; As[ak + 1][ar] = av.y;
    As[ak + 2][ar] = av.z; As[ak + 3][ar] = av.w;
    __syncthreads();
#pragma unroll
    for (int kk = 0; kk < 16; ++kk) {
      float a[4], bv[4];
      *(float4*)a = *(const float4*)&As[kk][ty << 2];
      *(float4*)bv = *(const float4*)&Bs[kk][tx << 2];
#pragma unroll
      for (int i = 0; i < 4; ++i)
#pragma unroll
        for (int j = 0; j < 4; ++j) acc[i][j] += a[i] * bv[j];
    }
    __syncthreads();
  }
  // epilogue: out[b][h][l][d], n = h*32+d (4 consecutive d, same head)
#pragma unroll
  for (int i = 0; i < 4; ++i) {
    int mi = m0 + (ty << 2) + i;
    int bb = mi >> 10;
    int l = mi & (L_DIM - 1);
    int n = n0 + (tx << 2);
    int hh = n >> 5, d = n & 31;
    float4 o4 = make_float4(acc[i][0], acc[i][1], acc[i][2], acc[i][3]);
    *(float4*)&out[((((size_t)bb << 3) + hh) * L_DIM + l) * D_DIM + d] = o4;
  }
}

// ---------------------------------------------------------------------------
// Kernel 3: fused attention. Block = (b, 16-row q-tile), 256 threads:
// tid -> head = tid>>5, row = (tid>>1)&15, half = tid&1 (half of dh).
// tk tile computed once per block in LDS, shared by all 8 heads.
// Causal: additive -10000 on k>=q; for q>=1 those terms underflow to exactly
// 0 in fp32, so k-tiles are skipped past the q-tile (row 0 fixed by kernel 4).
// ---------------------------------------------------------------------------
__global__ __launch_bounds__(256) void attn_kernel(
    const float* __restrict__ Q, const float* __restrict__ K,
    const float* __restrict__ V,
    const double* __restrict__ qpq, const float* __restrict__ sg,
    const float* __restrict__ bs, const float* __restrict__ t_in,
    const int* __restrict__ imask, float* __restrict__ out) {
  __shared__ float kf[H_DIM][TK][D_DIM];      // 32 KB
  __shared__ float vf[H_DIM][TK][D_DIM];      // 32 KB
  __shared__ float tkt[TQ][TK + 1];           // padded: conflict-free col reads
  __shared__ double qq[TQ][TD];
  __shared__ double kq[TK][9];                // padded (bank spread)
  __shared__ float qs[TQ][TD], qb[TQ][TD];
  __shared__ float ks[TK][9], kb[TK][9];      // padded (9j+d is bank-bijective)
  __shared__ float trow[TQ], tcol[TK];

  const int tid = threadIdx.x;
  const int b = blockIdx.x >> 6;              // / (L/TQ) = /64
  const int q0 = (blockIdx.x & 63) << 4;
  const int h = tid >> 5;
  const int row = (tid >> 1) & 15;
  const int half = tid & 1;
  const int qglob = q0 + row;

  // q-side features (once per block)
  if (tid < TQ * TD) {
    int i = tid >> 3, d = tid & 7;
    size_t base = (size_t)(b * L_DIM + q0 + i) * TD + d;
    qq[i][d] = qpq[base];
    qs[i][d] = sg[base];
    qb[i][d] = bs[base];
  }
  if (tid < TQ) trow[tid] = t_in[b * L_DIM + q0 + tid];

  // Q row-half into registers
  float qreg[16];
  {
    const float* qp = &Q[(((size_t)b * H_DIM + h) * L_DIM + qglob) * D_DIM + half * 16];
#pragma unroll
    for (int u = 0; u < 4; ++u) *(float4*)&qreg[u * 4] = *(const float4*)&qp[u * 4];
  }
  float qabs = 0.f;
#pragma unroll
  for (int d = 0; d < 16; ++d) qabs += fabsf(qreg[d]);
  qabs += __shfl_xor(qabs, 1);
  const float qmask = qabs > 0.f ? 1.f : 0.f;

  float m = -1e30f, lsum = 0.f;
  float acc[16];
#pragma unroll
  for (int d = 0; d < 16; ++d) acc[d] = 0.f;

  // rows q0..q0+15 need k <= q0+14 (rest underflow to 0); row 0 fixed later
  const int ntiles = ((q0 + TQ - 2) >> 5) + 1;

  for (int kt = 0; kt < ntiles; ++kt) {
    const int k0 = kt << 5;
    __syncthreads();  // previous compute done before restaging
    // stage K,V (per head contiguous: 256 float4 per head)
#pragma unroll
    for (int hh = 0; hh < H_DIM; ++hh) {
      const float4* srck = (const float4*)&K[(((size_t)b * H_DIM + hh) * L_DIM + k0) * D_DIM];
      const float4* srcv = (const float4*)&V[(((size_t)b * H_DIM + hh) * L_DIM + k0) * D_DIM];
      ((float4*)kf)[hh * 256 + tid] = srck[tid];
      ((float4*)vf)[hh * 256 + tid] = srcv[tid];
    }
    {
      int j = tid >> 3, d = tid & 7;  // 32*8 = 256 exactly
      size_t base = (size_t)(b * L_DIM + k0 + j) * TD + d;
      kq[j][d] = qpq[base];
      ks[j][d] = sg[base];
      kb[j][d] = bs[base];
    }
    if (tid < TK) tcol[tid] = t_in[b * L_DIM + k0 + tid];
    __syncthreads();

    // tk tile: 512 pairs, 2 per thread
#pragma unroll
    for (int pp = 0; pp < 2; ++pp) {
      int p = tid + (pp << 8);
      int i = p >> 5, j = p & 31;
      float td2 = trow[i] - tcol[j];
      td2 *= td2;
      float a = 0.f;
#pragma unroll
      for (int d = 0; d < TD; ++d) {
        float sqd = qs[i][d], skd = ks[j][d];
        float denom = sqd * sqd + skd * skd;
        float inv = __builtin_amdgcn_rcpf(denom);
        float ee = __expf(-td2 * inv);
        float le = __builtin_amdgcn_sqrtf(2.f * sqd * skd * inv);
        double pd = qq[i][d] - kq[j][d];
        double r = pd * INV_TWO_PI_D;
        float th = (float)((r - rint(r)) * TWO_PI_D);
        float ce = __cosf(th);
        a += qb[i][d] * kb[j][d] * (le * ee * ce);
      }
      tkt[i][j] = a;
    }
    __syncthreads();

    // scores for this tile
    float s[TK];
    float tmax = -1e30f;
#pragma unroll
    for (int j = 0; j < TK; ++j) {
      const float4* kr = (const float4*)&kf[h][j][half * 16];
      float part = 0.f;
#pragma unroll
      for (int u = 0; u < 4; ++u) {
        float4 kv = kr[u];
        part += qreg[u * 4 + 0] * kv.x + qreg[u * 4 + 1] * kv.y +
                qreg[u * 4 + 2] * kv.z + qreg[u * 4 + 3] * kv.w;
      }
      part += __shfl_xor(part, 1);
      float sc = (part + tkt[row][j]) * SCALE;
      if (k0 + j >= qglob) sc += -10000.0f;
      s[j] = sc;
      tmax = fmaxf(tmax, sc);
    }
    float mnew = fmaxf(m, tmax);
    float c = __expf(m - mnew);
    lsum *= c;
#pragma unroll
    for (int d = 0; d < 16; ++d) acc[d] *= c;
#pragma unroll
    for (int j = 0; j < TK; ++j) {
      float pexp = __expf(s[j] - mnew);
      lsum += pexp;
      const float4* vr = (const float4*)&vf[h][j][half * 16];
#pragma unroll
      for (int u = 0; u < 4; ++u) {
        float4 vv = vr[u];
        acc[u * 4 + 0] += pexp * vv.x; acc[u * 4 + 1] += pexp * vv.y;
        acc[u * 4 + 2] += pexp * vv.z; acc[u * 4 + 3] += pexp * vv.w;
      }
    }
    m = mnew;
  }

  const float sc_o = (1.0f / lsum) * qmask * (float)imask[b * L_DIM + qglob];
  float* op = &out[((size_t)(b * L_DIM + qglob)) * 256 + h * D_DIM + half * 16];
#pragma unroll
  for (int u = 0; u < 4; ++u) {
    float4 o4 = make_float4(acc[u * 4 + 0] * sc_o, acc[u * 4 + 1] * sc_o,
                            acc[u * 4 + 2] * sc_o, acc[u * 4 + 3] * sc_o);
    ((float4*)op)[u] = o4;
  }
}

// ---------------------------------------------------------------------------
// Kernel 4: row-0 fixup. Row 0 gets -10000 on ALL keys -> softmax over all
// scores (shift-invariant). One block per b; group g = head (32 lanes each).
// Overwrites out[b][0][:]. Launched after attn_kernel (same stream).
// ---------------------------------------------------------------------------
__global__ __launch_bounds__(256) void row0_kernel(
    const float* __restrict__ Q, const float* __restrict__ K,
    const float* __restrict__ V,
    const double* __restrict__ qpq, const float* __restrict__ sg,
    const float* __restrict__ bs, const float* __restrict__ t_in,
    const int* __restrict__ imask, float* __restrict__ out) {
  const int b = blockIdx.x;
  const int tid = threadIdx.x;
  __shared__ float tkl[L_DIM];
  __shared__ float sc[H_DIM][L_DIM];
  __shared__ double qq0[TD];
  __shared__ float qs0[TD], qb0[TD];
  if (tid < TD) {
    size_t base = (size_t)b * L_DIM * TD + tid;
    qq0[tid] = qpq[base];
    qs0[tid] = sg[base];
    qb0[tid] = bs[base];
  }
  __syncthreads();
  const float t0 = t_in[(size_t)b * L_DIM];
  for (int j = tid; j < L_DIM; j += 256) {
    float tj = t_in[(size_t)b * L_DIM + j];
    float td2 = (t0 - tj) * (t0 - tj);
    float a = 0.f;
    size_t fb = (size_t)(b * L_DIM + j) * TD;
#pragma unroll
    for (int d = 0; d < TD; ++d) {
      float sqd = qs0[d], skd = sg[fb + d];
      float denom = sqd * sqd + skd * skd;
      float inv = __builtin_amdgcn_rcpf(denom);
      float ee = __expf(-td2 * inv);
      float le = __builtin_amdgcn_sqrtf(2.f * sqd * skd * inv);
      double pd = qq0[d] - qpq[fb + d];
      double r = pd * INV_TWO_PI_D;
      float th = (float)((r - rint(r)) * TWO_PI_D);
      a += qb0[d] * bs[fb + d] * (le * ee * __cosf(th));
    }
    tkl[j] = a;
  }
  __syncthreads();
  const int g = tid >> 5, gl = tid & 31;
  const float* Qp = &Q[(((size_t)b * H_DIM + g) * L_DIM) * D_DIM];
  float qreg[32];
#pragma unroll
  for (int u = 0; u < 8; ++u) *(float4*)&qreg[u * 4] = *(const float4*)&Qp[u * 4];
  float qabs = 0.f;
#pragma unroll
  for (int d = 0; d < 32; ++d) qabs += fabsf(qreg[d]);
  const float qm = qabs > 0.f ? 1.f : 0.f;
  float pmax = -1e30f;
  for (int j = gl; j < L_DIM; j += 32) {
    const float* Kp = &K[(((size_t)b * H_DIM + g) * L_DIM + j) * D_DIM];
    float dot = 0.f;
#pragma unroll
    for (int d = 0; d < 32; ++d) dot += qreg[d] * Kp[d];
    sc[g][j] = (dot + tkl[j]) * SCALE;
    pmax = fmaxf(pmax, sc[g][j]);
  }
#pragma unroll
  for (int o = 16; o >= 1; o >>= 1) pmax = fmaxf(pmax, __shfl_xor(pmax, o));
  float lsum = 0.f;
  for (int j = gl; j < L_DIM; j += 32) {
    float p = __expf(sc[g][j] - pmax);
    sc[g][j] = p;
    lsum += p;
  }
#pragma unroll
  for (int o = 16; o >= 1; o >>= 1) lsum += __shfl_xor(lsum, o);
  __syncthreads();
  float acc = 0.f;
  for (int j = 0; j < L_DIM; ++j)
    acc += sc[g][j] * V[(((size_t)b * H_DIM + g) * L_DIM + j) * D_DIM + gl];
  out[((size_t)b * L_DIM) * 256 + g * D_DIM + gl] =
      acc * (1.0f / lsum) * qm * (float)imask[b * L_DIM];
}

// ---------------------------------------------------------------------------
extern "C" void kernel_launch(void* const* d_in, const int* in_sizes, int n_in,
                              void* d_out, int out_size, void* d_ws, size_t ws_size,
                              hipStream_t stream) {
  (void)in_sizes; (void)n_in; (void)out_size; (void)ws_size;
  const float* query = (const float*)d_in[0];
  const float* input = (const float*)d_in[1];
  const int* imask = (const int*)d_in[2];
  const float* t_in = (const float*)d_in[3];
  // d_in[4] = att_bias (unused by reference)
  const float* Wq = (const float*)d_in[5];
  const float* Wk = (const float*)d_in[6];
  const float* Wv = (const float*)d_in[7];
  const float* pW1 = (const float*)d_in[8],  *pb1 = (const float*)d_in[9];
  const float* pW2 = (const float*)d_in[10], *pb2 = (const float*)d_in[11];
  const float* sW1 = (const float*)d_in[12], *sb1 = (const float*)d_in[13];
  const float* sW2 = (const float*)d_in[14], *sb2 = (const float*)d_in[15];
  const float* bW1 = (const float*)d_in[16], *bb1 = (const float*)d_in[17];
  const float* bW2 = (const float*)d_in[18], *bb2 = (const float*)d_in[19];
  float* out = (float*)d_out;

  const int M = B_DIM * L_DIM;  // 4096
  char* ws = (char*)d_ws;
  const size_t qkv_bytes = (size_t)M * 256 * sizeof(float);  // 4 MB each
  float* Qb = (float*)(ws);
  float* Kb = (float*)(ws + qkv_bytes);
  float* Vb = (float*)(ws + 2 * qkv_bytes);
  double* qpq = (double*)(ws + 3 * qkv_bytes);                       // 256 KB
  float* sg = (float*)(ws + 3 * qkv_bytes + (size_t)M * TD * 8);     // 128 KB
  float* bs = (float*)(ws + 3 * qkv_bytes + (size_t)M * TD * 8 + (size_t)M * TD * 4);

  time_feat_kernel<<<M / 256, 256, 0, stream>>>(
      t_in, pW1, pb1, pW2, pb2, sW1, sb1, sW2, sb2, bW1, bb1, bW2, bb2,
      qpq, sg, bs, M);
  gemm_qkv<<<256, 256, 0, stream>>>(query, Wq, Qb);
  gemm_qkv<<<256, 256, 0, stream>>>(input, Wk, Kb);
  gemm_qkv<<<256, 256, 0, stream>>>(input, Wv, Vb);
  attn_kernel<<<B_DIM * (L_DIM / TQ), 256, 0, stream>>>(
      Qb, Kb, Vb, qpq, sg, bs, t_in, imask, out);
  row0_kernel<<<B_DIM, 256, 0, stream>>>(
      Qb, Kb, Vb, qpq, sg, bs, t_in, imask, out);
}

// Round 2
// 272.454 us; speedup vs baseline: 1.3823x; 1.3823x over previous
//
#include <hip/hip_runtime.h>
#include <math.h>

// Problem constants (fixed-shape harness: B=4, L=1024, U=256, H=8, dh=32, td=8)
#define B_DIM 4
#define L_DIM 1024
#define H_DIM 8
#define D_DIM 32
#define TD 8
#define TQ 16
#define TK 32
#define NQT (L_DIM / TQ)      // 64 q-tiles
#define NTILES_TOT 1056       // sum over qt of ntiles(qt)
#define SCALE 0.17677669529663687f          // 1/sqrt(32)
#define TWO_PI_D 6.283185307179586476925287
#define INV_TWO_PI_D 0.15915494309189533577

// causal tiling: rows q0..q0+15 need k <= q0+14 -> k-tiles 0..(q0+14)/32
__device__ __forceinline__ int ntiles_of(int qt) { return (qt >> 1) + 1; }
// prefix sum of ntiles: qt=2m -> m^2+m ; qt=2m+1 -> (m+1)^2
__device__ __forceinline__ int off_of(int qt) {
  int m = qt >> 1;
  return (qt & 1) ? (m + 1) * (m + 1) : m * m + m;
}

// ---------------------------------------------------------------------------
// Kernel 1: per-position time features (fp64 MLPs; qpq kept double for
// accurate range reduction of cos at ~1e5 magnitudes).
// ---------------------------------------------------------------------------
__device__ __forceinline__ void mlp8(double t, const float* __restrict__ W1,
                                     const float* __restrict__ b1,
                                     const float* __restrict__ W2,
                                     const float* __restrict__ b2,
                                     double* o) {
  double h[TD];
#pragma unroll
  for (int d = 0; d < TD; ++d) {
    double v = t * (double)W1[d] + (double)b1[d];
    h[d] = v > 0.0 ? v : 0.0;
  }
#pragma unroll
  for (int e = 0; e < TD; ++e) {
    double v = (double)b2[e];
#pragma unroll
    for (int d = 0; d < TD; ++d) v += h[d] * (double)W2[d * TD + e];
    o[e] = v > 0.0 ? v : 0.0;
  }
}

__global__ __launch_bounds__(256) void time_feat_kernel(
    const float* __restrict__ t_in,
    const float* __restrict__ pW1, const float* __restrict__ pb1,
    const float* __restrict__ pW2, const float* __restrict__ pb2,
    const float* __restrict__ sW1, const float* __restrict__ sb1,
    const float* __restrict__ sW2, const float* __restrict__ sb2,
    const float* __restrict__ bW1, const float* __restrict__ bb1,
    const float* __restrict__ bW2, const float* __restrict__ bb2,
    double* __restrict__ qpq, float* __restrict__ sg, float* __restrict__ bs,
    int total) {
  int i = blockIdx.x * blockDim.x + threadIdx.x;
  if (i >= total) return;
  double t = (double)t_in[i];
  double o[TD];
  mlp8(t, pW1, pb1, pW2, pb2, o);
#pragma unroll
  for (int d = 0; d < TD; ++d) qpq[(size_t)i * TD + d] = TWO_PI_D * o[d] * t;
  mlp8(t, sW1, sb1, sW2, sb2, o);
#pragma unroll
  for (int d = 0; d < TD; ++d) sg[(size_t)i * TD + d] = (float)(o[d] + 1e-6);
  mlp8(t, bW1, bb1, bW2, bb2, o);
#pragma unroll
  for (int d = 0; d < TD; ++d) bs[(size_t)i * TD + d] = (float)o[d];
}

// ---------------------------------------------------------------------------
// Kernel 2: X[4096,256] @ W[256,256] -> out in [B][H][L][dh] layout.
// blockIdx.y selects (Wq,Q)/(Wk,K)/(Wv,V) -> one launch, 768 blocks.
// ---------------------------------------------------------------------------
__global__ __launch_bounds__(256) void gemm_qkv3(
    const float* __restrict__ Xq, const float* __restrict__ Xkv,
    const float* __restrict__ Wq, const float* __restrict__ Wk,
    const float* __restrict__ Wv,
    float* __restrict__ Qb, float* __restrict__ Kb, float* __restrict__ Vb) {
  const int z = blockIdx.y;
  const float* X = (z == 0) ? Xq : Xkv;
  const float* W = (z == 0) ? Wq : (z == 1) ? Wk : Wv;
  float* out = (z == 0) ? Qb : (z == 1) ? Kb : Vb;

  __shared__ float As[16][64];
  __shared__ float Bs[16][64];
  const int tid = threadIdx.x;
  const int m0 = (blockIdx.x >> 2) << 6;
  const int n0 = (blockIdx.x & 3) << 6;
  const int tx = tid & 15;
  const int ty = tid >> 4;
  const int ar = tid >> 2;
  const int ak = (tid & 3) << 2;
  const int brk = tid >> 4;
  const int bn = (tid & 15) << 2;
  float acc[4][4] = {{0.f}};
  for (int k0 = 0; k0 < 256; k0 += 16) {
    float4 av = *(const float4*)&X[(size_t)(m0 + ar) * 256 + k0 + ak];
    *(float4*)&Bs[brk][bn] = *(const float4*)&W[(size_t)(k0 + brk) * 256 + n0 + bn];
    As[ak + 0][ar] = av.x; As[ak + 1][ar] = av.y;
    As[ak + 2][ar] = av.z; As[ak + 3][ar] = av.w;
    __syncthreads();
#pragma unroll
    for (int kk = 0; kk < 16; ++kk) {
      float a[4], bv[4];
      *(float4*)a = *(const float4*)&As[kk][ty << 2];
      *(float4*)bv = *(const float4*)&Bs[kk][tx << 2];
#pragma unroll
      for (int i = 0; i < 4; ++i)
#pragma unroll
        for (int j = 0; j < 4; ++j) acc[i][j] += a[i] * bv[j];
    }
    __syncthreads();
  }
#pragma unroll
  for (int i = 0; i < 4; ++i) {
    int mi = m0 + (ty << 2) + i;
    int bb = mi >> 10;
    int l = mi & (L_DIM - 1);
    int n = n0 + (tx << 2);
    int hh = n >> 5, d = n & 31;
    float4 o4 = make_float4(acc[i][0], acc[i][1], acc[i][2], acc[i][3]);
    *(float4*)&out[((((size_t)bb << 3) + hh) * L_DIM + l) * D_DIM + d] = o4;
  }
}

// ---------------------------------------------------------------------------
// Kernel 3: tk tiles (head-independent, causal lower-triangle only) into a
// compact buffer: tkbuf[(b*1056 + off(qt) + kt)*512 + i*32 + j].
// Grid (32, 64, 4); blocks with kt >= ntiles(qt) exit immediately.
// ---------------------------------------------------------------------------
__global__ __launch_bounds__(256) void tk_kernel(
    const double* __restrict__ qpq, const float* __restrict__ sg,
    const float* __restrict__ bs, const float* __restrict__ t_in,
    float* __restrict__ tkbuf) {
  const int kt = blockIdx.x;
  const int qt = blockIdx.y;
  const int b = blockIdx.z;
  if (kt >= ntiles_of(qt)) return;
  const int q0 = qt << 4, k0 = kt << 5;
  __shared__ double qq[TQ][TD];
  __shared__ double kq[TK][9];
  __shared__ float qs[TQ][TD], qb[TQ][TD];
  __shared__ float ks[TK][9], kb[TK][9];
  __shared__ float trow[TQ], tcol[TK];
  const int tid = threadIdx.x;
  if (tid < TQ * TD) {
    int i = tid >> 3, d = tid & 7;
    size_t base = (size_t)(b * L_DIM + q0 + i) * TD + d;
    qq[i][d] = qpq[base]; qs[i][d] = sg[base]; qb[i][d] = bs[base];
  }
  {
    int j = tid >> 3, d = tid & 7;  // 32*8 = 256 exactly
    size_t base = (size_t)(b * L_DIM + k0 + j) * TD + d;
    kq[j][d] = qpq[base]; ks[j][d] = sg[base]; kb[j][d] = bs[base];
  }
  if (tid < TQ) trow[tid] = t_in[b * L_DIM + q0 + tid];
  if (tid < TK) tcol[tid] = t_in[b * L_DIM + k0 + tid];
  __syncthreads();
  float* dst = &tkbuf[(size_t)(b * NTILES_TOT + off_of(qt) + kt) * (TQ * TK)];
#pragma unroll
  for (int pp = 0; pp < 2; ++pp) {
    int p = tid + (pp << 8);
    int i = p >> 5, j = p & 31;
    float td2 = trow[i] - tcol[j];
    td2 *= td2;
    float a = 0.f;
#pragma unroll
    for (int d = 0; d < TD; ++d) {
      float sqd = qs[i][d], skd = ks[j][d];
      float denom = sqd * sqd + skd * skd;
      float inv = __builtin_amdgcn_rcpf(denom);
      float ee = __expf(-td2 * inv);
      float le = __builtin_amdgcn_sqrtf(2.f * sqd * skd * inv);
      double pd = qq[i][d] - kq[j][d];
      double r = pd * INV_TWO_PI_D;
      float th = (float)((r - rint(r)) * TWO_PI_D);
      float ce = __cosf(th);
      a += qb[i][d] * kb[j][d] * (le * ee * ce);
    }
    dst[p] = a;
  }
}

// ---------------------------------------------------------------------------
// Kernel 4: attention. Grid (64 qt, 8 h, 4 b) = 2048 blocks, 256 threads:
// thread = (row = tid>>4, c = tid&15); owns output dims d0=2c, 2c+1 and
// score columns j=c, c+16. p broadcast via intra-wave __shfl (rows/wave = 4).
// Row qglob==0 is NOT stored here (row0_kernel provides it).
// ---------------------------------------------------------------------------
__global__ __launch_bounds__(256) void attn_kernel(
    const float* __restrict__ Q, const float* __restrict__ K,
    const float* __restrict__ V, const float* __restrict__ tkbuf,
    const int* __restrict__ imask, float* __restrict__ out) {
  __shared__ float kf[TK][36];
  __shared__ float vf[TK][36];
  const int qt = blockIdx.x;
  const int h = blockIdx.y;
  const int b = blockIdx.z;
  const int tid = threadIdx.x;
  const int row = tid >> 4;
  const int c = tid & 15;
  const int qglob = (qt << 4) + row;
  const int d0 = c << 1;
  const size_t bh = ((size_t)b * H_DIM + h) * L_DIM;

  float qreg[32];
  {
    const float* qp = &Q[(bh + qglob) * D_DIM];
#pragma unroll
    for (int u = 0; u < 8; ++u) *(float4*)&qreg[u * 4] = *(const float4*)&qp[u * 4];
  }
  float qabs = 0.f;
#pragma unroll
  for (int d = 0; d < 32; ++d) qabs += fabsf(qreg[d]);
  const float qmask = qabs > 0.f ? 1.f : 0.f;

  float m = -1e30f, lsum = 0.f, acc0 = 0.f, acc1 = 0.f;
  const int nt = ntiles_of(qt);
  const float* tkbase = &tkbuf[(size_t)(b * NTILES_TOT + off_of(qt)) * (TQ * TK)];

  for (int kt = 0; kt < nt; ++kt) {
    const int k0 = kt << 5;
    __syncthreads();
    {
      const float4* srck = (const float4*)&K[(bh + k0) * D_DIM];
      const float4* srcv = (const float4*)&V[(bh + k0) * D_DIM];
      float4 k4 = srck[tid];
      float4 v4 = srcv[tid];
      int r = tid >> 3, c4 = (tid & 7) << 2;
      *(float4*)&kf[r][c4] = k4;
      *(float4*)&vf[r][c4] = v4;
    }
    __syncthreads();

    float tk0 = tkbase[kt * 512 + (row << 5) + c];
    float tk1 = tkbase[kt * 512 + (row << 5) + c + 16];
    float s0 = 0.f, s1 = 0.f;
#pragma unroll
    for (int u = 0; u < 8; ++u) {
      float4 a4 = *(const float4*)&qreg[u * 4];
      float4 k0v = *(const float4*)&kf[c][u * 4];
      float4 k1v = *(const float4*)&kf[c + 16][u * 4];
      s0 += a4.x * k0v.x + a4.y * k0v.y + a4.z * k0v.z + a4.w * k0v.w;
      s1 += a4.x * k1v.x + a4.y * k1v.y + a4.z * k1v.z + a4.w * k1v.w;
    }
    s0 = (s0 + tk0) * SCALE;
    s1 = (s1 + tk1) * SCALE;
    if (k0 + c >= qglob) s0 -= 10000.0f;
    if (k0 + c + 16 >= qglob) s1 -= 10000.0f;

    float tmax = fmaxf(s0, s1);
#pragma unroll
    for (int o = 1; o < 16; o <<= 1) tmax = fmaxf(tmax, __shfl_xor(tmax, o));
    float mnew = fmaxf(m, tmax);
    float cf = __expf(m - mnew);
    float p0 = __expf(s0 - mnew);
    float p1 = __expf(s1 - mnew);
    float psum = p0 + p1;
#pragma unroll
    for (int o = 1; o < 16; o <<= 1) psum += __shfl_xor(psum, o);
    lsum = lsum * cf + psum;
    acc0 *= cf; acc1 *= cf;

    const int lanebase = tid & 48;  // (row&3)*16, wave-local group base
#pragma unroll
    for (int j = 0; j < 32; ++j) {
      float pj = __shfl((j < 16) ? p0 : p1, lanebase + (j & 15), 64);
      float2 vv = *(const float2*)&vf[j][d0];
      acc0 = fmaf(pj, vv.x, acc0);
      acc1 = fmaf(pj, vv.y, acc1);
    }
    m = mnew;
  }

  if (qglob != 0) {
    const float sc_o = (1.0f / lsum) * qmask * (float)imask[b * L_DIM + qglob];
    float2 o2 = make_float2(acc0 * sc_o, acc1 * sc_o);
    *(float2*)&out[((size_t)(b * L_DIM + qglob)) * 256 + h * D_DIM + d0] = o2;
  }
}

// ---------------------------------------------------------------------------
// Kernel 5: row-0 (uniform -10000 row -> softmax over ALL keys). Grid (8 h,
// 4 b). tk row 0 gathered from tkbuf via symmetry: tk[b][0][j] = tk[b][j][0]
// = tile (qt=j>>4, kt=0), entry ((j&15)*32 + 0).
// ---------------------------------------------------------------------------
__global__ __launch_bounds__(256) void row0_kernel(
    const float* __restrict__ Q, const float* __restrict__ K,
    const float* __restrict__ V, const float* __restrict__ tkbuf,
    const int* __restrict__ imask, float* __restrict__ out) {
  const int h = blockIdx.x;
  const int b = blockIdx.y;
  const size_t bh = ((size_t)b * H_DIM + h) * L_DIM;
  const int tid = threadIdx.x;
  __shared__ float p_s[L_DIM];
  __shared__ float qsh[D_DIM];
  __shared__ float red[8][33];
  __shared__ float rtmp[4];

  if (tid < D_DIM) qsh[tid] = Q[bh * D_DIM + tid];
  __syncthreads();

  float lmax = -1e30f;
  for (int j = tid; j < L_DIM; j += 256) {
    float tkv = tkbuf[(size_t)(b * NTILES_TOT + off_of(j >> 4)) * 512 + (j & 15) * 32];
    const float* Kp = &K[(bh + j) * D_DIM];
    float dot = 0.f;
#pragma unroll
    for (int d = 0; d < D_DIM; ++d) dot += qsh[d] * Kp[d];
    float sc = (dot + tkv) * SCALE;
    p_s[j] = sc;
    lmax = fmaxf(lmax, sc);
  }
#pragma unroll
  for (int o = 1; o < 64; o <<= 1) lmax = fmaxf(lmax, __shfl_xor(lmax, o));
  if ((tid & 63) == 0) rtmp[tid >> 6] = lmax;
  __syncthreads();
  const float bmax = fmaxf(fmaxf(rtmp[0], rtmp[1]), fmaxf(rtmp[2], rtmp[3]));
  __syncthreads();

  float lsumv = 0.f;
  for (int j = tid; j < L_DIM; j += 256) {
    float p = __expf(p_s[j] - bmax);
    p_s[j] = p;
    lsumv += p;
  }
#pragma unroll
  for (int o = 1; o < 64; o <<= 1) lsumv += __shfl_xor(lsumv, o);
  if ((tid & 63) == 0) rtmp[tid >> 6] = lsumv;
  __syncthreads();
  const float bsum = rtmp[0] + rtmp[1] + rtmp[2] + rtmp[3];

  // PV: group g = tid>>5 handles j in [g*128, g*128+128), dim d = tid&31
  const int g = tid >> 5, d = tid & 31;
  float a = 0.f;
  for (int j = g * 128; j < g * 128 + 128; ++j)
    a = fmaf(p_s[j], V[(bh + j) * D_DIM + d], a);
  red[g][d] = a;
  __syncthreads();
  if (tid < D_DIM) {
    float acc = 0.f;
#pragma unroll
    for (int gg = 0; gg < 8; ++gg) acc += red[gg][tid];
    float qabs = 0.f;
#pragma unroll
    for (int dd = 0; dd < D_DIM; ++dd) qabs += fabsf(qsh[dd]);
    const float qm = qabs > 0.f ? 1.f : 0.f;
    out[((size_t)b * L_DIM) * 256 + h * D_DIM + tid] =
        acc * (1.0f / bsum) * qm * (float)imask[b * L_DIM];
  }
}

// ---------------------------------------------------------------------------
extern "C" void kernel_launch(void* const* d_in, const int* in_sizes, int n_in,
                              void* d_out, int out_size, void* d_ws, size_t ws_size,
                              hipStream_t stream) {
  (void)in_sizes; (void)n_in; (void)out_size; (void)ws_size;
  const float* query = (const float*)d_in[0];
  const float* input = (const float*)d_in[1];
  const int* imask = (const int*)d_in[2];
  const float* t_in = (const float*)d_in[3];
  const float* Wq = (const float*)d_in[5];
  const float* Wk = (const float*)d_in[6];
  const float* Wv = (const float*)d_in[7];
  const float* pW1 = (const float*)d_in[8],  *pb1 = (const float*)d_in[9];
  const float* pW2 = (const float*)d_in[10], *pb2 = (const float*)d_in[11];
  const float* sW1 = (const float*)d_in[12], *sb1 = (const float*)d_in[13];
  const float* sW2 = (const float*)d_in[14], *sb2 = (const float*)d_in[15];
  const float* bW1 = (const float*)d_in[16], *bb1 = (const float*)d_in[17];
  const float* bW2 = (const float*)d_in[18], *bb2 = (const float*)d_in[19];
  float* out = (float*)d_out;

  const int M = B_DIM * L_DIM;  // 4096
  char* ws = (char*)d_ws;
  const size_t qkv_bytes = (size_t)M * 256 * sizeof(float);  // 4 MB each
  float* Qb = (float*)(ws);
  float* Kb = (float*)(ws + qkv_bytes);
  float* Vb = (float*)(ws + 2 * qkv_bytes);
  char* p = ws + 3 * qkv_bytes;
  double* qpq = (double*)p;                 p += (size_t)M * TD * sizeof(double);
  float* sg = (float*)p;                    p += (size_t)M * TD * sizeof(float);
  float* bs = (float*)p;                    p += (size_t)M * TD * sizeof(float);
  float* tkbuf = (float*)p;                 // 4*1056*512*4 = 8.65 MB

  time_feat_kernel<<<M / 256, 256, 0, stream>>>(
      t_in, pW1, pb1, pW2, pb2, sW1, sb1, sW2, sb2, bW1, bb1, bW2, bb2,
      qpq, sg, bs, M);
  gemm_qkv3<<<dim3(256, 3), 256, 0, stream>>>(query, input, Wq, Wk, Wv, Qb, Kb, Vb);
  tk_kernel<<<dim3(32, NQT, B_DIM), 256, 0, stream>>>(qpq, sg, bs, t_in, tkbuf);
  attn_kernel<<<dim3(NQT, H_DIM, B_DIM), 256, 0, stream>>>(
      Qb, Kb, Vb, tkbuf, imask, out);
  row0_kernel<<<dim3(H_DIM, B_DIM), 256, 0, stream>>>(
      Qb, Kb, Vb, tkbuf, imask, out);
}

// Round 3
// 116.672 us; speedup vs baseline: 3.2279x; 2.3352x over previous
//
#include <hip/hip_runtime.h>
#include <math.h>

// Problem constants (fixed-shape harness: B=4, L=1024, U=256, H=8, dh=32, td=8)
#define B_DIM 4
#define L_DIM 1024
#define H_DIM 8
#define D_DIM 32
#define TD 8
#define TQ 16
#define TK 32
#define NQT (L_DIM / TQ)      // 64 q-tiles of 16
#define NTILES_TOT 1056       // sum over qt of ntiles(qt)
#define SCALE 0.17677669529663687f          // 1/sqrt(32)
#define TWO_PI_D 6.283185307179586476925287
#define INV_TWO_PI_D 0.15915494309189533577

typedef __attribute__((ext_vector_type(8))) short short8v;
typedef __attribute__((ext_vector_type(4))) float f32x4;

// causal tiling: rows q0..q0+15 need k <= q0+14 -> k-tiles 0..(q0+14)/32
__device__ __forceinline__ int ntiles_of(int qt) { return (qt >> 1) + 1; }
// prefix sum of ntiles: qt=2m -> m^2+m ; qt=2m+1 -> (m+1)^2
__device__ __forceinline__ int off_of(int qt) {
  int m = qt >> 1;
  return (qt & 1) ? (m + 1) * (m + 1) : m * m + m;
}

__device__ __forceinline__ unsigned short f2bf(float f) {
  unsigned u = __builtin_bit_cast(unsigned, f);
  u += 0x7FFFu + ((u >> 16) & 1u);
  return (unsigned short)(u >> 16);
}

// ---------------------------------------------------------------------------
// Kernel 1: per-position time features (fp64 MLPs; qpq kept double for
// accurate range reduction of cos at ~1e5 magnitudes).
// ---------------------------------------------------------------------------
__device__ __forceinline__ void mlp8(double t, const float* __restrict__ W1,
                                     const float* __restrict__ b1,
                                     const float* __restrict__ W2,
                                     const float* __restrict__ b2,
                                     double* o) {
  double h[TD];
#pragma unroll
  for (int d = 0; d < TD; ++d) {
    double v = t * (double)W1[d] + (double)b1[d];
    h[d] = v > 0.0 ? v : 0.0;
  }
#pragma unroll
  for (int e = 0; e < TD; ++e) {
    double v = (double)b2[e];
#pragma unroll
    for (int d = 0; d < TD; ++d) v += h[d] * (double)W2[d * TD + e];
    o[e] = v > 0.0 ? v : 0.0;
  }
}

__global__ __launch_bounds__(256) void time_feat_kernel(
    const float* __restrict__ t_in,
    const float* __restrict__ pW1, const float* __restrict__ pb1,
    const float* __restrict__ pW2, const float* __restrict__ pb2,
    const float* __restrict__ sW1, const float* __restrict__ sb1,
    const float* __restrict__ sW2, const float* __restrict__ sb2,
    const float* __restrict__ bW1, const float* __restrict__ bb1,
    const float* __restrict__ bW2, const float* __restrict__ bb2,
    double* __restrict__ qpq, float* __restrict__ sg, float* __restrict__ bs,
    int total) {
  int i = blockIdx.x * blockDim.x + threadIdx.x;
  if (i >= total) return;
  double t = (double)t_in[i];
  double o[TD];
  mlp8(t, pW1, pb1, pW2, pb2, o);
#pragma unroll
  for (int d = 0; d < TD; ++d) qpq[(size_t)i * TD + d] = TWO_PI_D * o[d] * t;
  mlp8(t, sW1, sb1, sW2, sb2, o);
#pragma unroll
  for (int d = 0; d < TD; ++d) sg[(size_t)i * TD + d] = (float)(o[d] + 1e-6);
  mlp8(t, bW1, bb1, bW2, bb2, o);
#pragma unroll
  for (int d = 0; d < TD; ++d) bs[(size_t)i * TD + d] = (float)o[d];
}

// ---------------------------------------------------------------------------
// Kernel 2: X[4096,256] @ W[256,256] -> out in [B][H][L][dh] layout.
// ---------------------------------------------------------------------------
__global__ __launch_bounds__(256) void gemm_qkv3(
    const float* __restrict__ Xq, const float* __restrict__ Xkv,
    const float* __restrict__ Wq, const float* __restrict__ Wk,
    const float* __restrict__ Wv,
    float* __restrict__ Qb, float* __restrict__ Kb, float* __restrict__ Vb) {
  const int z = blockIdx.y;
  const float* X = (z == 0) ? Xq : Xkv;
  const float* W = (z == 0) ? Wq : (z == 1) ? Wk : Wv;
  float* out = (z == 0) ? Qb : (z == 1) ? Kb : Vb;

  __shared__ float As[16][64];
  __shared__ float Bs[16][64];
  const int tid = threadIdx.x;
  const int m0 = (blockIdx.x >> 2) << 6;
  const int n0 = (blockIdx.x & 3) << 6;
  const int tx = tid & 15;
  const int ty = tid >> 4;
  const int ar = tid >> 2;
  const int ak = (tid & 3) << 2;
  const int brk = tid >> 4;
  const int bn = (tid & 15) << 2;
  float acc[4][4] = {{0.f}};
  for (int k0 = 0; k0 < 256; k0 += 16) {
    float4 av = *(const float4*)&X[(size_t)(m0 + ar) * 256 + k0 + ak];
    *(float4*)&Bs[brk][bn] = *(const float4*)&W[(size_t)(k0 + brk) * 256 + n0 + bn];
    As[ak + 0][ar] = av.x; As[ak + 1][ar] = av.y;
    As[ak + 2][ar] = av.z; As[ak + 3][ar] = av.w;
    __syncthreads();
#pragma unroll
    for (int kk = 0; kk < 16; ++kk) {
      float a[4], bv[4];
      *(float4*)a = *(const float4*)&As[kk][ty << 2];
      *(float4*)bv = *(const float4*)&Bs[kk][tx << 2];
#pragma unroll
      for (int i = 0; i < 4; ++i)
#pragma unroll
        for (int j = 0; j < 4; ++j) acc[i][j] += a[i] * bv[j];
    }
    __syncthreads();
  }
#pragma unroll
  for (int i = 0; i < 4; ++i) {
    int mi = m0 + (ty << 2) + i;
    int bb = mi >> 10;
    int l = mi & (L_DIM - 1);
    int n = n0 + (tx << 2);
    int hh = n >> 5, d = n & 31;
    float4 o4 = make_float4(acc[i][0], acc[i][1], acc[i][2], acc[i][3]);
    *(float4*)&out[((((size_t)bb << 3) + hh) * L_DIM + l) * D_DIM + d] = o4;
  }
}

// ---------------------------------------------------------------------------
// Kernel 3: tk tiles stored in MFMA C-fragment order:
// tile base (b*1056 + off(qt) + kt)*512; within tile, idx = s*256 + l*4 + r
// <-> (q-row i = (l>>4)*4 + r, k-col j = s*16 + (l&15)). Attention then reads
// one coalesced float4 per lane per 16x16 subtile.
// ---------------------------------------------------------------------------
__global__ __launch_bounds__(256) void tk_kernel(
    const double* __restrict__ qpq, const float* __restrict__ sg,
    const float* __restrict__ bs, const float* __restrict__ t_in,
    float* __restrict__ tkbuf) {
  const int kt = blockIdx.x;
  const int qt = blockIdx.y;
  const int b = blockIdx.z;
  if (kt >= ntiles_of(qt)) return;
  const int q0 = qt << 4, k0 = kt << 5;
  __shared__ double qq[TQ][TD];
  __shared__ double kq[TK][9];
  __shared__ float qs[TQ][TD], qb[TQ][TD];
  __shared__ float ks[TK][9], kb[TK][9];
  __shared__ float trow[TQ], tcol[TK];
  const int tid = threadIdx.x;
  if (tid < TQ * TD) {
    int i = tid >> 3, d = tid & 7;
    size_t base = (size_t)(b * L_DIM + q0 + i) * TD + d;
    qq[i][d] = qpq[base]; qs[i][d] = sg[base]; qb[i][d] = bs[base];
  }
  {
    int j = tid >> 3, d = tid & 7;  // 32*8 = 256 exactly
    size_t base = (size_t)(b * L_DIM + k0 + j) * TD + d;
    kq[j][d] = qpq[base]; ks[j][d] = sg[base]; kb[j][d] = bs[base];
  }
  if (tid < TQ) trow[tid] = t_in[b * L_DIM + q0 + tid];
  if (tid < TK) tcol[tid] = t_in[b * L_DIM + k0 + tid];
  __syncthreads();
  float* dst = &tkbuf[(size_t)(b * NTILES_TOT + off_of(qt) + kt) * (TQ * TK)];
#pragma unroll
  for (int pp = 0; pp < 2; ++pp) {
    int idx = tid + (pp << 8);
    int lr = (idx >> 2) & 63;
    int r = idx & 3;
    int i = ((lr >> 4) << 2) | r;
    int j = ((idx >> 8) << 4) | (lr & 15);
    float td2 = trow[i] - tcol[j];
    td2 *= td2;
    float a = 0.f;
#pragma unroll
    for (int d = 0; d < TD; ++d) {
      float sqd = qs[i][d], skd = ks[j][d];
      float denom = sqd * sqd + skd * skd;
      float inv = __builtin_amdgcn_rcpf(denom);
      float ee = __expf(-td2 * inv);
      float le = __builtin_amdgcn_sqrtf(2.f * sqd * skd * inv);
      double pd = qq[i][d] - kq[j][d];
      double rr = pd * INV_TWO_PI_D;
      float th = (float)((rr - rint(rr)) * TWO_PI_D);
      float ce = __cosf(th);
      a += qb[i][d] * kb[j][d] * (le * ee * ce);
    }
    dst[idx] = a;
  }
}

// ---------------------------------------------------------------------------
// Kernel 4: MFMA flash attention. Block = (b, h, 64-row q-chunk), 4 waves x
// 16 q-rows. K/V chunk (64 keys x 32 dims) staged in LDS as bf16 fragments;
// P routed wave-locally through LDS (C-frag -> A-frag). Contraction-dim
// placement is identical on both operands of each MFMA pair, so correctness
// is independent of the HW's internal k-ordering; only the verified C/D
// layout (row=(l>>4)*4+reg, col=l&15) is used for masks/tk/softmax.
// qc mapped longest-first; all 512 blocks co-resident (8 waves/CU).
// ---------------------------------------------------------------------------
__global__ __launch_bounds__(256) void attn_mfma_kernel(
    const float* __restrict__ Q, const float* __restrict__ K,
    const float* __restrict__ V, const float* __restrict__ tkbuf,
    const int* __restrict__ imask, float* __restrict__ out) {
  __shared__ __align__(16) unsigned short lds_k[4 * 64 * 8];   // [kt][lane][j]
  __shared__ __align__(16) unsigned short lds_v[4 * 64 * 8];   // [kh*2+dt][lane][j]
  __shared__ __align__(16) unsigned short lds_p[4][2 * 64 * 8];// per wave [kh][lane][j]

  const int qc = 15 - (int)blockIdx.x;  // longest-first
  const int h = blockIdx.y;
  const int b = blockIdx.z;
  const int tid = threadIdx.x;
  const int w = tid >> 6;
  const int l = tid & 63;
  const int lg = l >> 4;
  const int lc = l & 15;
  const size_t bh = ((size_t)b * H_DIM + h) * L_DIM;
  const int qbase = qc * 64 + w * 16;
  const int qt_g = qbase >> 4;

  // Q A-frag: row = qbase+lc, dims lg*8 + j
  short8v qfrag;
  float qabs_l;
  {
    const float* qp = &Q[(bh + qbase + lc) * D_DIM + lg * 8];
    float4 q0 = *(const float4*)qp;
    float4 q1 = *(const float4*)(qp + 4);
    qfrag[0] = (short)f2bf(q0.x); qfrag[1] = (short)f2bf(q0.y);
    qfrag[2] = (short)f2bf(q0.z); qfrag[3] = (short)f2bf(q0.w);
    qfrag[4] = (short)f2bf(q1.x); qfrag[5] = (short)f2bf(q1.y);
    qfrag[6] = (short)f2bf(q1.z); qfrag[7] = (short)f2bf(q1.w);
    qabs_l = fabsf(q0.x) + fabsf(q0.y) + fabsf(q0.z) + fabsf(q0.w) +
             fabsf(q1.x) + fabsf(q1.y) + fabsf(q1.z) + fabsf(q1.w);
  }
  qabs_l += __shfl_xor(qabs_l, 16);
  qabs_l += __shfl_xor(qabs_l, 32);  // row-lc |Q| sum, replicated across groups
  const float qm = (qabs_l > 0.f) ? 1.f : 0.f;

  f32x4 O0 = {0.f, 0.f, 0.f, 0.f};
  f32x4 O1 = {0.f, 0.f, 0.f, 0.f};
  float mrow[4] = {-1e30f, -1e30f, -1e30f, -1e30f};
  float lrow[4] = {0.f, 0.f, 0.f, 0.f};
  const float* tk_qt = &tkbuf[(size_t)(b * NTILES_TOT + off_of(qt_g)) * 512];
  unsigned short* Pw = lds_p[w];

  for (int kc = 0; kc <= qc; ++kc) {
    const int k0 = kc * 64;
    __syncthreads();  // prior readers of lds_k/lds_v done
#pragma unroll
    for (int it = 0; it < 2; ++it) {
      int lin = tid + (it << 8);
      int rr = lin >> 3;
      int d0 = (lin & 7) << 2;
      float4 kv = *(const float4*)&K[(bh + k0 + rr) * D_DIM + d0];
      float4 vv = *(const float4*)&V[(bh + k0 + rr) * D_DIM + d0];
      float kva[4] = {kv.x, kv.y, kv.z, kv.w};
      float vva[4] = {vv.x, vv.y, vv.z, vv.w};
#pragma unroll
      for (int u = 0; u < 4; ++u) {
        int d = d0 + u;
        lds_k[((rr >> 4) * 64 + (d >> 3) * 16 + (rr & 15)) * 8 + (d & 7)] = f2bf(kva[u]);
        lds_v[(((rr >> 5) * 2 + (d >> 4)) * 64 + ((rr & 31) >> 3) * 16 + (d & 15)) * 8 + (rr & 7)] = f2bf(vva[u]);
      }
    }
    __syncthreads();

    // scores: 4 k-subtiles of 16
    float s[4][4];
    const bool diag = (kc == qc);
#pragma unroll
    for (int kt = 0; kt < 4; ++kt) {
      short8v kfrag = *(const short8v*)&lds_k[(kt * 64 + l) * 8];
      f32x4 z = {0.f, 0.f, 0.f, 0.f};
      f32x4 sv = __builtin_amdgcn_mfma_f32_16x16x32_bf16(qfrag, kfrag, z, 0, 0, 0);
      float4 tk4 = *(const float4*)&tk_qt[(size_t)(kc * 2 + (kt >> 1)) * 512 + (kt & 1) * 256 + l * 4];
      float tka[4] = {tk4.x, tk4.y, tk4.z, tk4.w};
      int col = k0 + kt * 16 + lc;
#pragma unroll
      for (int r = 0; r < 4; ++r) {
        float val = (sv[r] + tka[r]) * SCALE;
        if (diag && col >= qbase + lg * 4 + r) val = -10000.0f;
        s[kt][r] = val;
      }
    }

    // online softmax per row r; write P (bf16) to wave-local LDS in A-frag map
#pragma unroll
    for (int r = 0; r < 4; ++r) {
      float tmax = fmaxf(fmaxf(s[0][r], s[1][r]), fmaxf(s[2][r], s[3][r]));
      tmax = fmaxf(tmax, __shfl_xor(tmax, 1));
      tmax = fmaxf(tmax, __shfl_xor(tmax, 2));
      tmax = fmaxf(tmax, __shfl_xor(tmax, 4));
      tmax = fmaxf(tmax, __shfl_xor(tmax, 8));
      float mnew = fmaxf(mrow[r], tmax);
      float cf = __expf(mrow[r] - mnew);
      mrow[r] = mnew;
      float p0 = __expf(s[0][r] - mnew);
      float p1 = __expf(s[1][r] - mnew);
      float p2 = __expf(s[2][r] - mnew);
      float p3 = __expf(s[3][r] - mnew);
      float psum = (p0 + p1) + (p2 + p3);
      psum += __shfl_xor(psum, 1);
      psum += __shfl_xor(psum, 2);
      psum += __shfl_xor(psum, 4);
      psum += __shfl_xor(psum, 8);
      lrow[r] = lrow[r] * cf + psum;
      O0[r] *= cf;
      O1[r] *= cf;
      // kt: kh=kt>>1; addr = kh*512 + (kt&1)*256 + (lc>>3)*128 + rr_p*8 + (lc&7)
      const int pb = ((lc >> 3) << 7) + ((lg * 4 + r) << 3) + (lc & 7);
      Pw[pb] = f2bf(p0);
      Pw[pb + 256] = f2bf(p1);
      Pw[pb + 512] = f2bf(p2);
      Pw[pb + 768] = f2bf(p3);
    }

    // PV: O[dt] += P[kh] x V[kh][dt]
#pragma unroll
    for (int kh = 0; kh < 2; ++kh) {
      short8v pfrag = *(const short8v*)&Pw[(kh * 64 + l) * 8];
      short8v vf0 = *(const short8v*)&lds_v[((kh * 2 + 0) * 64 + l) * 8];
      short8v vf1 = *(const short8v*)&lds_v[((kh * 2 + 1) * 64 + l) * 8];
      O0 = __builtin_amdgcn_mfma_f32_16x16x32_bf16(pfrag, vf0, O0, 0, 0, 0);
      O1 = __builtin_amdgcn_mfma_f32_16x16x32_bf16(pfrag, vf1, O1, 0, 0, 0);
    }
  }

  // epilogue
#pragma unroll
  for (int r = 0; r < 4; ++r) {
    int rr = lg * 4 + r;
    int qrow = qbase + rr;
    float qmr = __shfl(qm, rr);  // lane rr holds row rr's mask
    float im = (float)imask[b * L_DIM + qrow];
    float scl = (1.f / lrow[r]) * qmr * im;
    if (qrow != 0) {
      float* op = &out[((size_t)(b * L_DIM + qrow)) * 256 + h * D_DIM];
      op[lc] = O0[r] * scl;
      op[16 + lc] = O1[r] * scl;
    }
  }
}

// ---------------------------------------------------------------------------
// Kernel 5: row-0 (uniform -10000 row -> softmax over ALL keys). Grid (8 h,
// 4 b). tk row 0 via symmetry tk[b][0][j] = tk[b][j][0] = tile(qt=j>>4,kt=0),
// frag idx = ((i>>2)<<6)|(i&3) with i = j&15.
// ---------------------------------------------------------------------------
__global__ __launch_bounds__(256) void row0_kernel(
    const float* __restrict__ Q, const float* __restrict__ K,
    const float* __restrict__ V, const float* __restrict__ tkbuf,
    const int* __restrict__ imask, float* __restrict__ out) {
  const int h = blockIdx.x;
  const int b = blockIdx.y;
  const size_t bh = ((size_t)b * H_DIM + h) * L_DIM;
  const int tid = threadIdx.x;
  __shared__ float p_s[L_DIM];
  __shared__ float qsh[D_DIM];
  __shared__ float red[8][33];
  __shared__ float rtmp[4];

  if (tid < D_DIM) qsh[tid] = Q[bh * D_DIM + tid];
  __syncthreads();

  float lmax = -1e30f;
  for (int j = tid; j < L_DIM; j += 256) {
    int i = j & 15;
    float tkv = tkbuf[(size_t)(b * NTILES_TOT + off_of(j >> 4)) * 512 +
                      (((i >> 2) << 6) | (i & 3))];
    const float* Kp = &K[(bh + j) * D_DIM];
    float dot = 0.f;
#pragma unroll
    for (int d = 0; d < D_DIM; ++d) dot += qsh[d] * Kp[d];
    float sc = (dot + tkv) * SCALE;
    p_s[j] = sc;
    lmax = fmaxf(lmax, sc);
  }
#pragma unroll
  for (int o = 1; o < 64; o <<= 1) lmax = fmaxf(lmax, __shfl_xor(lmax, o));
  if ((tid & 63) == 0) rtmp[tid >> 6] = lmax;
  __syncthreads();
  const float bmax = fmaxf(fmaxf(rtmp[0], rtmp[1]), fmaxf(rtmp[2], rtmp[3]));
  __syncthreads();

  float lsumv = 0.f;
  for (int j = tid; j < L_DIM; j += 256) {
    float p = __expf(p_s[j] - bmax);
    p_s[j] = p;
    lsumv += p;
  }
#pragma unroll
  for (int o = 1; o < 64; o <<= 1) lsumv += __shfl_xor(lsumv, o);
  if ((tid & 63) == 0) rtmp[tid >> 6] = lsumv;
  __syncthreads();
  const float bsum = rtmp[0] + rtmp[1] + rtmp[2] + rtmp[3];

  const int g = tid >> 5, d = tid & 31;
  float a = 0.f;
  for (int j = g * 128; j < g * 128 + 128; ++j)
    a = fmaf(p_s[j], V[(bh + j) * D_DIM + d], a);
  red[g][d] = a;
  __syncthreads();
  if (tid < D_DIM) {
    float acc = 0.f;
#pragma unroll
    for (int gg = 0; gg < 8; ++gg) acc += red[gg][tid];
    float qabs = 0.f;
#pragma unroll
    for (int dd = 0; dd < D_DIM; ++dd) qabs += fabsf(qsh[dd]);
    const float qmv = qabs > 0.f ? 1.f : 0.f;
    out[((size_t)b * L_DIM) * 256 + h * D_DIM + tid] =
        acc * (1.0f / bsum) * qmv * (float)imask[b * L_DIM];
  }
}

// ---------------------------------------------------------------------------
extern "C" void kernel_launch(void* const* d_in, const int* in_sizes, int n_in,
                              void* d_out, int out_size, void* d_ws, size_t ws_size,
                              hipStream_t stream) {
  (void)in_sizes; (void)n_in; (void)out_size; (void)ws_size;
  const float* query = (const float*)d_in[0];
  const float* input = (const float*)d_in[1];
  const int* imask = (const int*)d_in[2];
  const float* t_in = (const float*)d_in[3];
  const float* Wq = (const float*)d_in[5];
  const float* Wk = (const float*)d_in[6];
  const float* Wv = (const float*)d_in[7];
  const float* pW1 = (const float*)d_in[8],  *pb1 = (const float*)d_in[9];
  const float* pW2 = (const float*)d_in[10], *pb2 = (const float*)d_in[11];
  const float* sW1 = (const float*)d_in[12], *sb1 = (const float*)d_in[13];
  const float* sW2 = (const float*)d_in[14], *sb2 = (const float*)d_in[15];
  const float* bW1 = (const float*)d_in[16], *bb1 = (const float*)d_in[17];
  const float* bW2 = (const float*)d_in[18], *bb2 = (const float*)d_in[19];
  float* out = (float*)d_out;

  const int M = B_DIM * L_DIM;  // 4096
  char* ws = (char*)d_ws;
  const size_t qkv_bytes = (size_t)M * 256 * sizeof(float);  // 4 MB each
  float* Qb = (float*)(ws);
  float* Kb = (float*)(ws + qkv_bytes);
  float* Vb = (float*)(ws + 2 * qkv_bytes);
  char* p = ws + 3 * qkv_bytes;
  double* qpq = (double*)p;                 p += (size_t)M * TD * sizeof(double);
  float* sg = (float*)p;                    p += (size_t)M * TD * sizeof(float);
  float* bs = (float*)p;                    p += (size_t)M * TD * sizeof(float);
  float* tkbuf = (float*)p;                 // 4*1056*512*4 = 8.65 MB

  time_feat_kernel<<<M / 256, 256, 0, stream>>>(
      t_in, pW1, pb1, pW2, pb2, sW1, sb1, sW2, sb2, bW1, bb1, bW2, bb2,
      qpq, sg, bs, M);
  gemm_qkv3<<<dim3(256, 3), 256, 0, stream>>>(query, input, Wq, Wk, Wv, Qb, Kb, Vb);
  tk_kernel<<<dim3(32, NQT, B_DIM), 256, 0, stream>>>(qpq, sg, bs, t_in, tkbuf);
  attn_mfma_kernel<<<dim3(16, H_DIM, B_DIM), 256, 0, stream>>>(
      Qb, Kb, Vb, tkbuf, imask, out);
  row0_kernel<<<dim3(H_DIM, B_DIM), 256, 0, stream>>>(
      Qb, Kb, Vb, tkbuf, imask, out);
}

// Round 4
// 93.754 us; speedup vs baseline: 4.0170x; 1.2445x over previous
//
#include <hip/hip_runtime.h>
#include <math.h>

// Problem constants (fixed-shape harness: B=4, L=1024, U=256, H=8, dh=32, td=8)
#define B_DIM 4
#define L_DIM 1024
#define H_DIM 8
#define D_DIM 32
#define TD 8
#define NTILES_TOT 1056       // sum over 16-row q-tiles of k-tile count
#define SCALE 0.17677669529663687f          // 1/sqrt(32)
#define TWO_PI_F 6.2831853071795864769f

typedef unsigned short ushort_t;
typedef __attribute__((ext_vector_type(8))) short short8v;
typedef __attribute__((ext_vector_type(4))) float f32x4;

// causal tiling helpers (16-row q-tiles, 32-key k-tiles)
__device__ __forceinline__ int ntiles_of(int qt) { return (qt >> 1) + 1; }
__device__ __forceinline__ int off_of(int qt) {
  int m = qt >> 1;
  return (qt & 1) ? (m + 1) * (m + 1) : m * m + m;
}

__device__ __forceinline__ ushort_t f2bf(float f) {
  unsigned u = __builtin_bit_cast(unsigned, f);
  u += 0x7FFFu + ((u >> 16) & 1u);
  return (ushort_t)(u >> 16);
}
__device__ __forceinline__ float bf2f(ushort_t h) {
  return __builtin_bit_cast(float, ((unsigned)h) << 16);
}
__device__ __forceinline__ short8v pack84(float4 a, float4 b) {
  short8v r;
  r[0] = (short)f2bf(a.x); r[1] = (short)f2bf(a.y);
  r[2] = (short)f2bf(a.z); r[3] = (short)f2bf(a.w);
  r[4] = (short)f2bf(b.x); r[5] = (short)f2bf(b.y);
  r[6] = (short)f2bf(b.z); r[7] = (short)f2bf(b.w);
  return r;
}

// ---------------------------------------------------------------------------
// Kernel 1: per-position time features. fp64 MLPs (4096 positions, cheap).
// Stores ptf = frac(period*t) as float (fp64 range reduction done HERE once;
// cos(2*pi*(ptf_i - ptf_j)) is then pure fp32 in tk), sigma+1e-6, basis.
// ---------------------------------------------------------------------------
__device__ __forceinline__ void mlp8(double t, const float* __restrict__ W1,
                                     const float* __restrict__ b1,
                                     const float* __restrict__ W2,
                                     const float* __restrict__ b2,
                                     double* o) {
  double h[TD];
#pragma unroll
  for (int d = 0; d < TD; ++d) {
    double v = t * (double)W1[d] + (double)b1[d];
    h[d] = v > 0.0 ? v : 0.0;
  }
#pragma unroll
  for (int e = 0; e < TD; ++e) {
    double v = (double)b2[e];
#pragma unroll
    for (int d = 0; d < TD; ++d) v += h[d] * (double)W2[d * TD + e];
    o[e] = v > 0.0 ? v : 0.0;
  }
}

__global__ __launch_bounds__(256) void time_feat_kernel(
    const float* __restrict__ t_in,
    const float* __restrict__ pW1, const float* __restrict__ pb1,
    const float* __restrict__ pW2, const float* __restrict__ pb2,
    const float* __restrict__ sW1, const float* __restrict__ sb1,
    const float* __restrict__ sW2, const float* __restrict__ sb2,
    const float* __restrict__ bW1, const float* __restrict__ bb1,
    const float* __restrict__ bW2, const float* __restrict__ bb2,
    float* __restrict__ ptf, float* __restrict__ sg, float* __restrict__ bs,
    int total) {
  int i = blockIdx.x * blockDim.x + threadIdx.x;
  if (i >= total) return;
  double t = (double)t_in[i];
  double o[TD];
  mlp8(t, pW1, pb1, pW2, pb2, o);
#pragma unroll
  for (int d = 0; d < TD; ++d) {
    double pt = o[d] * t;                 // qpq / (2*pi)
    ptf[(size_t)i * TD + d] = (float)(pt - floor(pt));
  }
  mlp8(t, sW1, sb1, sW2, sb2, o);
#pragma unroll
  for (int d = 0; d < TD; ++d) sg[(size_t)i * TD + d] = (float)(o[d] + 1e-6);
  mlp8(t, bW1, bb1, bW2, bb2, o);
#pragma unroll
  for (int d = 0; d < TD; ++d) bs[(size_t)i * TD + d] = (float)o[d];
}

// ---------------------------------------------------------------------------
// Kernel 2a: X[4096,256] fp32 -> bf16 A-fragment layout
// Xf[(row>>4)*8 + kt][l][j] with l=(k&31)>>3*16+(row&15)... element (row, k):
// idx = ((row>>4)*8 + (k>>5))*512 + (((k>>3)&3)*16 + (row&15))*8 + (k&7)
// ---------------------------------------------------------------------------
__global__ __launch_bounds__(256) void xprep_kernel(
    const float* __restrict__ Xq, const float* __restrict__ Xi,
    ushort_t* __restrict__ Xfq, ushort_t* __restrict__ Xfi) {
  const float* X = blockIdx.y ? Xi : Xq;
  ushort_t* O = blockIdx.y ? Xfi : Xfq;
  int lin = blockIdx.x * 256 + threadIdx.x;   // 131072 = 4096 rows * 32 octets
  int row = lin >> 5, q = lin & 31;
  const float* src = &X[(size_t)row * 256 + q * 8];
  short8v f = pack84(*(const float4*)src, *(const float4*)(src + 4));
  size_t idx = ((size_t)((row >> 4) * 8 + (q >> 2)) * 64 + (q & 3) * 16 + (row & 15)) * 8;
  *(short8v*)&O[idx] = f;
}

// ---------------------------------------------------------------------------
// Kernel 2b: W[256,256] fp32 -> bf16 B-fragment layout (transposed gather)
// element (k, n) -> Wf[((z*8 + k>>5)*16 + n>>4)*512 + (((k>>3)&3)*16 + (n&15))*8 + (k&7)]
// ---------------------------------------------------------------------------
__global__ __launch_bounds__(256) void wprep_kernel(
    const float* __restrict__ Wq, const float* __restrict__ Wk,
    const float* __restrict__ Wv, ushort_t* __restrict__ Wf) {
  int z = blockIdx.y;
  const float* W = (z == 0) ? Wq : (z == 1) ? Wk : Wv;
  int lin = blockIdx.x * 256 + threadIdx.x;   // 8192 per z
  int kt = lin >> 10, g = (lin >> 8) & 3, n = lin & 255;
  float v[8];
#pragma unroll
  for (int i = 0; i < 8; ++i) v[i] = W[(size_t)(kt * 32 + g * 8 + i) * 256 + n];
  short8v f;
#pragma unroll
  for (int i = 0; i < 8; ++i) f[i] = (short)f2bf(v[i]);
  size_t idx = ((size_t)((z * 8 + kt) * 16 + (n >> 4)) * 64 + g * 16 + (n & 15)) * 8;
  *(short8v*)&Wf[idx] = f;
}

// ---------------------------------------------------------------------------
// Kernel 3: MFMA GEMM, zero LDS / zero barriers. Grid (32 m-tiles of 128,
// 4 n-tiles of 64, 3 z). 4 waves: wave (wm,wn) owns 64x32. Per K-tile (32):
// 4 afrag + 2 bfrag coalesced 16B global loads + 8 MFMAs.
// Writes fp32 [b][h][l][d] (all z) + bf16 frag layout (z=0,1 -> Qf,Kf).
// ---------------------------------------------------------------------------
__global__ __launch_bounds__(256) void gemm_mfma(
    const ushort_t* __restrict__ Xfq, const ushort_t* __restrict__ Xfi,
    const ushort_t* __restrict__ Wf,
    float* __restrict__ Qb, float* __restrict__ Kb, float* __restrict__ Vb,
    ushort_t* __restrict__ Qf, ushort_t* __restrict__ Kf) {
  const int z = blockIdx.z;
  const ushort_t* Xf = (z == 0) ? Xfq : Xfi;
  float* outf = (z == 0) ? Qb : (z == 1) ? Kb : Vb;
  ushort_t* of16 = (z == 0) ? Qf : Kf;   // unused when z==2
  const int m0t = blockIdx.x * 8;        // base row-tile (8 tiles of 16 = 128 rows)
  const int n0 = blockIdx.y * 64;
  const int tid = threadIdx.x;
  const int w = tid >> 6, l = tid & 63, lg = l >> 4, lc = l & 15;
  const int wm = w >> 1, wn = w & 1;

  f32x4 acc[4][2];
#pragma unroll
  for (int mi = 0; mi < 4; ++mi)
#pragma unroll
    for (int ni = 0; ni < 2; ++ni) acc[mi][ni] = (f32x4){0.f, 0.f, 0.f, 0.f};

  for (int kt0 = 0; kt0 < 8; ++kt0) {
    short8v a[4], bfr[2];
#pragma unroll
    for (int mi = 0; mi < 4; ++mi)
      a[mi] = *(const short8v*)&Xf[((size_t)(m0t + wm * 4 + mi) * 8 + kt0) * 512 + l * 8];
#pragma unroll
    for (int ni = 0; ni < 2; ++ni)
      bfr[ni] = *(const short8v*)&Wf[((size_t)(z * 8 + kt0) * 16 + (n0 >> 4) + wn * 2 + ni) * 512 + l * 8];
#pragma unroll
    for (int mi = 0; mi < 4; ++mi)
#pragma unroll
      for (int ni = 0; ni < 2; ++ni)
        acc[mi][ni] = __builtin_amdgcn_mfma_f32_16x16x32_bf16(a[mi], bfr[ni], acc[mi][ni], 0, 0, 0);
  }

#pragma unroll
  for (int mi = 0; mi < 4; ++mi) {
#pragma unroll
    for (int ni = 0; ni < 2; ++ni) {
      const int col = n0 + wn * 32 + ni * 16 + lc;
      const int hh = col >> 5, d = col & 31;
#pragma unroll
      for (int r = 0; r < 4; ++r) {
        const int row = (m0t + wm * 4 + mi) * 16 + lg * 4 + r;
        const int bb = row >> 10, lr = row & (L_DIM - 1);
        const float v = acc[mi][ni][r];
        outf[((size_t)(bb * H_DIM + hh) * L_DIM + lr) * D_DIM + d] = v;
        if (z != 2) {
          size_t fi = ((size_t)((bb * H_DIM + hh) * 64 + (lr >> 4))) * 512 +
                      ((d >> 3) * 16 + (lr & 15)) * 8 + (d & 7);
          of16[fi] = f2bf(v);
        }
      }
    }
  }
}

// ---------------------------------------------------------------------------
// Kernel 4: V fp32 [b][h][k][d] -> bf16 B-fragment layout for PV:
// element (k, d) of group kg=k>>5: Vf[((bh*32+kg)*2 + d>>4)*512 + (((k>>3)&3)*16 + (d&15))*8 + (k&7)]
// ---------------------------------------------------------------------------
__global__ __launch_bounds__(256) void vprep_kernel(
    const float* __restrict__ Vb, ushort_t* __restrict__ Vf) {
  const int tid = threadIdx.x;
  const int bh = blockIdx.x >> 4;
  const int kg = (blockIdx.x & 15) * 2 + (tid >> 7);
  const int dt = (tid >> 6) & 1, lgv = (tid >> 4) & 3, lc = tid & 15;
  const size_t base = ((size_t)bh * L_DIM + kg * 32 + lgv * 8) * D_DIM + dt * 16 + lc;
  short8v f;
#pragma unroll
  for (int i = 0; i < 8; ++i) f[i] = (short)f2bf(Vb[base + (size_t)i * D_DIM]);
  size_t idx = (((size_t)bh * 32 + kg) * 2 + dt) * 512 + (lgv * 16 + lc) * 8;
  *(short8v*)&Vf[idx] = f;
}

// ---------------------------------------------------------------------------
// Kernel 5: tk tiles in MFMA C-fragment order (unchanged layout from R3):
// tile (b, qt, kt): idx = s*256 + l*4 + r <-> (i=(l>>4)*4+r, j=s*16+(l&15)).
// Inner loop now pure fp32 (ptf pre-reduced).
// ---------------------------------------------------------------------------
__global__ __launch_bounds__(256) void tk_kernel(
    const float* __restrict__ ptf, const float* __restrict__ sg,
    const float* __restrict__ bs, const float* __restrict__ t_in,
    float* __restrict__ tkbuf) {
  const int kt = blockIdx.x;
  const int qt = blockIdx.y;
  const int b = blockIdx.z;
  if (kt >= ntiles_of(qt)) return;
  const int q0 = qt << 4, k0 = kt << 5;
  __shared__ float ptq[16][TD], ptk[32][9];
  __shared__ float qs[16][TD], qb[16][TD];
  __shared__ float ks[32][9], kb[32][9];
  __shared__ float trow[16], tcol[32];
  const int tid = threadIdx.x;
  if (tid < 16 * TD) {
    int i = tid >> 3, d = tid & 7;
    size_t base = (size_t)(b * L_DIM + q0 + i) * TD + d;
    ptq[i][d] = ptf[base]; qs[i][d] = sg[base]; qb[i][d] = bs[base];
  }
  {
    int j = tid >> 3, d = tid & 7;  // 32*8 = 256 exactly
    size_t base = (size_t)(b * L_DIM + k0 + j) * TD + d;
    ptk[j][d] = ptf[base]; ks[j][d] = sg[base]; kb[j][d] = bs[base];
  }
  if (tid < 16) trow[tid] = t_in[b * L_DIM + q0 + tid];
  if (tid < 32) tcol[tid] = t_in[b * L_DIM + k0 + tid];
  __syncthreads();
  float* dst = &tkbuf[(size_t)(b * NTILES_TOT + off_of(qt) + kt) * 512];
#pragma unroll
  for (int pp = 0; pp < 2; ++pp) {
    int idx = tid + (pp << 8);
    int lr = (idx >> 2) & 63;
    int r = idx & 3;
    int i = ((lr >> 4) << 2) | r;
    int j = ((idx >> 8) << 4) | (lr & 15);
    float td2 = trow[i] - tcol[j];
    td2 *= td2;
    float a = 0.f;
#pragma unroll
    for (int d = 0; d < TD; ++d) {
      float sqd = qs[i][d], skd = ks[j][d];
      float denom = sqd * sqd + skd * skd;
      float inv = __builtin_amdgcn_rcpf(denom);
      float ee = __expf(-td2 * inv);
      float le = __builtin_amdgcn_sqrtf(2.f * sqd * skd * inv);
      float dq = ptq[i][d] - ptk[j][d];
      float ce = __cosf(TWO_PI_F * dq);
      a += qb[i][d] * kb[j][d] * (le * ee * ce);
    }
    dst[idx] = a;
  }
}

// ---------------------------------------------------------------------------
// Kernel 6: MFMA flash attention, zero barriers. Block=(qc,h,b), 4 waves x 16
// q-rows. Q/K/V frags loaded directly from pre-packed bf16 global buffers
// (one coalesced 16B read each). LDS only for the wave-PRIVATE P transpose.
// Balanced qc map: co-scheduled blocks (z and z+2) get qc and 15-qc.
// ---------------------------------------------------------------------------
__global__ __launch_bounds__(256) void attn_mfma_kernel(
    const ushort_t* __restrict__ Qf, const ushort_t* __restrict__ Kf,
    const ushort_t* __restrict__ Vf, const float* __restrict__ tkbuf,
    const int* __restrict__ imask, float* __restrict__ out) {
  __shared__ __align__(16) ushort_t lds_p[4][1024];  // per-wave P (8 KB)

  const int h = blockIdx.y;
  const int b = blockIdx.z;
  const int qc = (b >= 2) ? (int)blockIdx.x : 15 - (int)blockIdx.x;
  const int tid = threadIdx.x;
  const int w = tid >> 6;
  const int l = tid & 63;
  const int lg = l >> 4;
  const int lc = l & 15;
  const int qbase = qc * 64 + w * 16;
  const int qt = qbase >> 4;
  const int fb = (b * H_DIM + h) * 64;   // frag-tile base (16-row tiles)
  const int vb = (b * H_DIM + h) * 32;   // V-group base (32-key groups)

  short8v qfrag = *(const short8v*)&Qf[((size_t)(fb + qt)) * 512 + l * 8];
  float qabs_l = 0.f;
#pragma unroll
  for (int j = 0; j < 8; ++j) qabs_l += fabsf(bf2f((ushort_t)qfrag[j]));
  qabs_l += __shfl_xor(qabs_l, 16);
  qabs_l += __shfl_xor(qabs_l, 32);
  const float qm = (qabs_l > 0.f) ? 1.f : 0.f;

  f32x4 O0 = {0.f, 0.f, 0.f, 0.f};
  f32x4 O1 = {0.f, 0.f, 0.f, 0.f};
  float mrow[4] = {-1e30f, -1e30f, -1e30f, -1e30f};
  float lrow[4] = {0.f, 0.f, 0.f, 0.f};
  const float* tk_qt = &tkbuf[(size_t)(b * NTILES_TOT + off_of(qt)) * 512];
  ushort_t* Pw = lds_p[w];

  for (int kc = 0; kc <= qc; ++kc) {
    float s[4][4];
    const bool diag = (kc == qc);
#pragma unroll
    for (int kt = 0; kt < 4; ++kt) {
      short8v kfrag = *(const short8v*)&Kf[((size_t)(fb + kc * 4 + kt)) * 512 + l * 8];
      f32x4 z4 = {0.f, 0.f, 0.f, 0.f};
      f32x4 sv = __builtin_amdgcn_mfma_f32_16x16x32_bf16(qfrag, kfrag, z4, 0, 0, 0);
      float4 tk4 = *(const float4*)&tk_qt[(size_t)(kc * 2 + (kt >> 1)) * 512 + (kt & 1) * 256 + l * 4];
      float tka[4] = {tk4.x, tk4.y, tk4.z, tk4.w};
      const int col = kc * 64 + kt * 16 + lc;
#pragma unroll
      for (int r = 0; r < 4; ++r) {
        float val = (sv[r] + tka[r]) * SCALE;
        if (diag && col >= qbase + lg * 4 + r) val = -10000.0f;
        s[kt][r] = val;
      }
    }

#pragma unroll
    for (int r = 0; r < 4; ++r) {
      float tmax = fmaxf(fmaxf(s[0][r], s[1][r]), fmaxf(s[2][r], s[3][r]));
      tmax = fmaxf(tmax, __shfl_xor(tmax, 1));
      tmax = fmaxf(tmax, __shfl_xor(tmax, 2));
      tmax = fmaxf(tmax, __shfl_xor(tmax, 4));
      tmax = fmaxf(tmax, __shfl_xor(tmax, 8));
      float mnew = fmaxf(mrow[r], tmax);
      float cf = __expf(mrow[r] - mnew);
      mrow[r] = mnew;
      float p0 = __expf(s[0][r] - mnew);
      float p1 = __expf(s[1][r] - mnew);
      float p2 = __expf(s[2][r] - mnew);
      float p3 = __expf(s[3][r] - mnew);
      float psum = (p0 + p1) + (p2 + p3);
      psum += __shfl_xor(psum, 1);
      psum += __shfl_xor(psum, 2);
      psum += __shfl_xor(psum, 4);
      psum += __shfl_xor(psum, 8);
      lrow[r] = lrow[r] * cf + psum;
      O0[r] *= cf;
      O1[r] *= cf;
      const int pb = ((lc >> 3) << 7) + ((lg * 4 + r) << 3) + (lc & 7);
      Pw[pb] = f2bf(p0);
      Pw[pb + 256] = f2bf(p1);
      Pw[pb + 512] = f2bf(p2);
      Pw[pb + 768] = f2bf(p3);
    }

#pragma unroll
    for (int kh = 0; kh < 2; ++kh) {
      short8v pfrag = *(const short8v*)&Pw[(kh * 64 + l) * 8];
      const size_t vbase = ((size_t)(vb + kc * 2 + kh)) * 1024 + l * 8;
      short8v vf0 = *(const short8v*)&Vf[vbase];
      short8v vf1 = *(const short8v*)&Vf[vbase + 512];
      O0 = __builtin_amdgcn_mfma_f32_16x16x32_bf16(pfrag, vf0, O0, 0, 0, 0);
      O1 = __builtin_amdgcn_mfma_f32_16x16x32_bf16(pfrag, vf1, O1, 0, 0, 0);
    }
  }

#pragma unroll
  for (int r = 0; r < 4; ++r) {
    const int rr = lg * 4 + r;
    const int qrow = qbase + rr;
    float qmr = __shfl(qm, rr);
    float im = (float)imask[b * L_DIM + qrow];
    float scl = (1.f / lrow[r]) * qmr * im;
    if (qrow != 0) {
      float* op = &out[((size_t)(b * L_DIM + qrow)) * 256 + h * D_DIM];
      op[lc] = O0[r] * scl;
      op[16 + lc] = O1[r] * scl;
    }
  }
}

// ---------------------------------------------------------------------------
// Kernel 7: row-0 (uniform -10000 row -> softmax over ALL keys). Grid (8,4).
// tk row 0 via symmetry tk[b][0][j] = tile(qt=j>>4, kt=0), frag idx
// ((i>>2)<<6)|(i&3), i=j&15. Uses fp32 Q/K/V buffers.
// ---------------------------------------------------------------------------
__global__ __launch_bounds__(256) void row0_kernel(
    const float* __restrict__ Q, const float* __restrict__ K,
    const float* __restrict__ V, const float* __restrict__ tkbuf,
    const int* __restrict__ imask, float* __restrict__ out) {
  const int h = blockIdx.x;
  const int b = blockIdx.y;
  const size_t bh = ((size_t)b * H_DIM + h) * L_DIM;
  const int tid = threadIdx.x;
  __shared__ float p_s[L_DIM];
  __shared__ float qsh[D_DIM];
  __shared__ float red[8][33];
  __shared__ float rtmp[4];

  if (tid < D_DIM) qsh[tid] = Q[bh * D_DIM + tid];
  __syncthreads();

  float lmax = -1e30f;
  for (int j = tid; j < L_DIM; j += 256) {
    int i = j & 15;
    float tkv = tkbuf[(size_t)(b * NTILES_TOT + off_of(j >> 4)) * 512 +
                      (((i >> 2) << 6) | (i & 3))];
    const float* Kp = &K[(bh + j) * D_DIM];
    float dot = 0.f;
#pragma unroll
    for (int d = 0; d < D_DIM; ++d) dot += qsh[d] * Kp[d];
    float sc = (dot + tkv) * SCALE;
    p_s[j] = sc;
    lmax = fmaxf(lmax, sc);
  }
#pragma unroll
  for (int o = 1; o < 64; o <<= 1) lmax = fmaxf(lmax, __shfl_xor(lmax, o));
  if ((tid & 63) == 0) rtmp[tid >> 6] = lmax;
  __syncthreads();
  const float bmax = fmaxf(fmaxf(rtmp[0], rtmp[1]), fmaxf(rtmp[2], rtmp[3]));
  __syncthreads();

  float lsumv = 0.f;
  for (int j = tid; j < L_DIM; j += 256) {
    float p = __expf(p_s[j] - bmax);
    p_s[j] = p;
    lsumv += p;
  }
#pragma unroll
  for (int o = 1; o < 64; o <<= 1) lsumv += __shfl_xor(lsumv, o);
  if ((tid & 63) == 0) rtmp[tid >> 6] = lsumv;
  __syncthreads();
  const float bsum = rtmp[0] + rtmp[1] + rtmp[2] + rtmp[3];

  const int g = tid >> 5, d = tid & 31;
  float a = 0.f;
  for (int j = g * 128; j < g * 128 + 128; ++j)
    a = fmaf(p_s[j], V[(bh + j) * D_DIM + d], a);
  red[g][d] = a;
  __syncthreads();
  if (tid < D_DIM) {
    float acc = 0.f;
#pragma unroll
    for (int gg = 0; gg < 8; ++gg) acc += red[gg][tid];
    float qabs = 0.f;
#pragma unroll
    for (int dd = 0; dd < D_DIM; ++dd) qabs += fabsf(qsh[dd]);
    const float qmv = qabs > 0.f ? 1.f : 0.f;
    out[((size_t)b * L_DIM) * 256 + h * D_DIM + tid] =
        acc * (1.0f / bsum) * qmv * (float)imask[b * L_DIM];
  }
}

// ---------------------------------------------------------------------------
extern "C" void kernel_launch(void* const* d_in, const int* in_sizes, int n_in,
                              void* d_out, int out_size, void* d_ws, size_t ws_size,
                              hipStream_t stream) {
  (void)in_sizes; (void)n_in; (void)out_size; (void)ws_size;
  const float* query = (const float*)d_in[0];
  const float* input = (const float*)d_in[1];
  const int* imask = (const int*)d_in[2];
  const float* t_in = (const float*)d_in[3];
  const float* Wq = (const float*)d_in[5];
  const float* Wk = (const float*)d_in[6];
  const float* Wv = (const float*)d_in[7];
  const float* pW1 = (const float*)d_in[8],  *pb1 = (const float*)d_in[9];
  const float* pW2 = (const float*)d_in[10], *pb2 = (const float*)d_in[11];
  const float* sW1 = (const float*)d_in[12], *sb1 = (const float*)d_in[13];
  const float* sW2 = (const float*)d_in[14], *sb2 = (const float*)d_in[15];
  const float* bW1 = (const float*)d_in[16], *bb1 = (const float*)d_in[17];
  const float* bW2 = (const float*)d_in[18], *bb2 = (const float*)d_in[19];
  float* out = (float*)d_out;

  const int M = B_DIM * L_DIM;  // 4096
  char* p = (char*)d_ws;
  float* Qb = (float*)p;      p += (size_t)M * 256 * 4;   // 4 MB
  float* Kb = (float*)p;      p += (size_t)M * 256 * 4;
  float* Vb = (float*)p;      p += (size_t)M * 256 * 4;
  ushort_t* Qf = (ushort_t*)p; p += (size_t)M * 256 * 2;  // 2 MB
  ushort_t* Kf = (ushort_t*)p; p += (size_t)M * 256 * 2;
  ushort_t* Vf = (ushort_t*)p; p += (size_t)M * 256 * 2;
  ushort_t* Xfq = (ushort_t*)p; p += (size_t)M * 256 * 2;
  ushort_t* Xfi = (ushort_t*)p; p += (size_t)M * 256 * 2;
  ushort_t* Wfb = (ushort_t*)p; p += (size_t)3 * 256 * 256 * 2;
  float* ptf = (float*)p;     p += (size_t)M * TD * 4;
  float* sg = (float*)p;      p += (size_t)M * TD * 4;
  float* bs = (float*)p;      p += (size_t)M * TD * 4;
  float* tkbuf = (float*)p;   // 4*1056*512*4 = 8.65 MB

  time_feat_kernel<<<M / 256, 256, 0, stream>>>(
      t_in, pW1, pb1, pW2, pb2, sW1, sb1, sW2, sb2, bW1, bb1, bW2, bb2,
      ptf, sg, bs, M);
  xprep_kernel<<<dim3(512, 2), 256, 0, stream>>>(query, input, Xfq, Xfi);
  wprep_kernel<<<dim3(32, 3), 256, 0, stream>>>(Wq, Wk, Wv, Wfb);
  gemm_mfma<<<dim3(32, 4, 3), 256, 0, stream>>>(Xfq, Xfi, Wfb, Qb, Kb, Vb, Qf, Kf);
  tk_kernel<<<dim3(32, 64, 4), 256, 0, stream>>>(ptf, sg, bs, t_in, tkbuf);
  vprep_kernel<<<512, 256, 0, stream>>>(Vb, Vf);
  attn_mfma_kernel<<<dim3(16, H_DIM, B_DIM), 256, 0, stream>>>(
      Qf, Kf, Vf, tkbuf, imask, out);
  row0_kernel<<<dim3(H_DIM, B_DIM), 256, 0, stream>>>(
      Qb, Kb, Vb, tkbuf, imask, out);
}

// Round 5
// 62.075 us; speedup vs baseline: 6.0669x; 1.5103x over previous
//
#include <hip/hip_runtime.h>
#include <math.h>

// Problem constants (fixed-shape harness: B=4, L=1024, U=256, H=8, dh=32, td=8)
#define B_DIM 4
#define L_DIM 1024
#define H_DIM 8
#define D_DIM 32
#define TD 8
#define NTILES_TOT 1056       // sum over 16-row q-tiles of k-tile count
#define SCALE 0.17677669529663687f          // 1/sqrt(32)
#define TWO_PI_F 6.2831853071795864769f

typedef unsigned short ushort_t;
typedef __attribute__((ext_vector_type(8))) short short8v;
typedef __attribute__((ext_vector_type(4))) float f32x4;

// causal tiling helpers (16-row q-tiles, 32-key k-tiles)
__device__ __forceinline__ int ntiles_of(int qt) { return (qt >> 1) + 1; }
__device__ __forceinline__ int off_of(int qt) {
  int m = qt >> 1;
  return (qt & 1) ? (m + 1) * (m + 1) : m * m + m;
}

__device__ __forceinline__ ushort_t f2bf(float f) {
  unsigned u = __builtin_bit_cast(unsigned, f);
  u += 0x7FFFu + ((u >> 16) & 1u);
  return (ushort_t)(u >> 16);
}
__device__ __forceinline__ float bf2f(ushort_t h) {
  return __builtin_bit_cast(float, ((unsigned)h) << 16);
}
__device__ __forceinline__ short8v pack84(float4 a, float4 b) {
  short8v r;
  r[0] = (short)f2bf(a.x); r[1] = (short)f2bf(a.y);
  r[2] = (short)f2bf(a.z); r[3] = (short)f2bf(a.w);
  r[4] = (short)f2bf(b.x); r[5] = (short)f2bf(b.y);
  r[6] = (short)f2bf(b.z); r[7] = (short)f2bf(b.w);
  return r;
}

// ---------------------------------------------------------------------------
// Kernel 1: PREP = time-features + X bf16-frag pack + W bf16-frag pack.
//  blk <  512 : time features, thread per (pos i, mlp z, out e); fp64 math
//               (identical op order to R4's mlp8 per-output slice).
//  blk < 1536 : X[4096,256] -> A-frag bf16 layout (2 inputs).
//  blk < 1632 : W[256,256]x3 -> B-frag bf16 layout.
// ---------------------------------------------------------------------------
__global__ __launch_bounds__(256) void prep_kernel(
    const float* __restrict__ t_in,
    const float* __restrict__ pW1, const float* __restrict__ pb1,
    const float* __restrict__ pW2, const float* __restrict__ pb2,
    const float* __restrict__ sW1, const float* __restrict__ sb1,
    const float* __restrict__ sW2, const float* __restrict__ sb2,
    const float* __restrict__ bW1, const float* __restrict__ bb1,
    const float* __restrict__ bW2, const float* __restrict__ bb2,
    float* __restrict__ ptf, float* __restrict__ sg, float* __restrict__ bs,
    const float* __restrict__ Xq, const float* __restrict__ Xi,
    ushort_t* __restrict__ Xfq, ushort_t* __restrict__ Xfi,
    const float* __restrict__ Wq, const float* __restrict__ Wk,
    const float* __restrict__ Wv, ushort_t* __restrict__ Wf) {
  const int blk = blockIdx.x;
  const int tid = threadIdx.x;
  if (blk < 512) {
    const int lin = blk * 256 + tid;        // 131072 slots = 4096 pos * 32
    const int i = lin >> 5;
    const int slot = lin & 31;
    const int z = slot >> 3, e = slot & 7;  // z==3 slots idle
    if (z == 3) return;
    const float* W1 = (z == 0) ? pW1 : (z == 1) ? sW1 : bW1;
    const float* b1 = (z == 0) ? pb1 : (z == 1) ? sb1 : bb1;
    const float* W2 = (z == 0) ? pW2 : (z == 1) ? sW2 : bW2;
    const float* b2 = (z == 0) ? pb2 : (z == 1) ? sb2 : bb2;
    const double t = (double)t_in[i];
    double acc = (double)b2[e];
#pragma unroll
    for (int d = 0; d < 8; ++d) {
      double hv = t * (double)W1[d] + (double)b1[d];
      hv = hv > 0.0 ? hv : 0.0;
      acc += hv * (double)W2[d * 8 + e];
    }
    acc = acc > 0.0 ? acc : 0.0;
    const size_t o = (size_t)i * TD + e;
    if (z == 0) {
      double pt = acc * t;                  // period*t; frac in fp64 here once
      ptf[o] = (float)(pt - floor(pt));
    } else if (z == 1) {
      sg[o] = (float)(acc + 1e-6);
    } else {
      bs[o] = (float)acc;
    }
  } else if (blk < 1536) {
    const int xb = blk - 512;               // 0..1023
    const float* X = (xb < 512) ? Xq : Xi;
    ushort_t* O = (xb < 512) ? Xfq : Xfi;
    const int lin = (xb & 511) * 256 + tid; // 131072 = 4096 rows * 32 octets
    const int row = lin >> 5, q = lin & 31;
    const float* src = &X[(size_t)row * 256 + q * 8];
    short8v f = pack84(*(const float4*)src, *(const float4*)(src + 4));
    size_t idx = ((size_t)((row >> 4) * 8 + (q >> 2)) * 64 + (q & 3) * 16 + (row & 15)) * 8;
    *(short8v*)&O[idx] = f;
  } else {
    const int wb = blk - 1536;              // 0..95
    const int z = wb >> 5;
    const float* W = (z == 0) ? Wq : (z == 1) ? Wk : Wv;
    const int lin = (wb & 31) * 256 + tid;  // 0..8191
    const int kt = lin >> 10, g = (lin >> 8) & 3, n = lin & 255;
    short8v f;
#pragma unroll
    for (int i2 = 0; i2 < 8; ++i2)
      f[i2] = (short)f2bf(W[(size_t)(kt * 32 + g * 8 + i2) * 256 + n]);
    size_t idx = ((size_t)((z * 8 + kt) * 16 + (n >> 4)) * 64 + g * 16 + (n & 15)) * 8;
    *(short8v*)&Wf[idx] = f;
  }
}

// ---------------------------------------------------------------------------
// Kernel 2: WORK = QKV MFMA GEMM (blk < 384) + tk tiles (blk >= 384, exact
// live-tile decode, no dead blocks).
// GEMM: zero LDS/barriers; writes ONLY bf16 frag buffers (Qf/Kf A-frag for
// scores; Vf B-frag for PV -- vprep folded in).
// tk: fragment-order output tiles (idx = s*256 + l*4 + r).
// ---------------------------------------------------------------------------
__global__ __launch_bounds__(256) void work_kernel(
    const ushort_t* __restrict__ Xfq, const ushort_t* __restrict__ Xfi,
    const ushort_t* __restrict__ Wf,
    ushort_t* __restrict__ Qf, ushort_t* __restrict__ Kf,
    ushort_t* __restrict__ Vf,
    const float* __restrict__ ptf, const float* __restrict__ sg,
    const float* __restrict__ bs, const float* __restrict__ t_in,
    float* __restrict__ tkbuf) {
  __shared__ float ptq[16][TD], ptk[32][9];
  __shared__ float qs[16][TD], qb[16][TD];
  __shared__ float ks[32][9], kb[32][9];
  __shared__ float trow[16], tcol[32];
  const int blk = blockIdx.x;
  const int tid = threadIdx.x;

  if (blk < 384) {
    const int z = blk >> 7;                 // 0..2 (Q,K,V)
    const int rem = blk & 127;
    const int m0t = (rem & 31) * 8;         // 8 row-tiles of 16 = 128 rows
    const int n0 = (rem >> 5) * 64;
    const ushort_t* Xf = (z == 0) ? Xfq : Xfi;
    const int w = tid >> 6, l = tid & 63, lg = l >> 4, lc = l & 15;
    const int wm = w >> 1, wn = w & 1;

    f32x4 acc[4][2];
#pragma unroll
    for (int mi = 0; mi < 4; ++mi)
#pragma unroll
      for (int ni = 0; ni < 2; ++ni) acc[mi][ni] = (f32x4){0.f, 0.f, 0.f, 0.f};

    for (int kt0 = 0; kt0 < 8; ++kt0) {
      short8v a[4], bfr[2];
#pragma unroll
      for (int mi = 0; mi < 4; ++mi)
        a[mi] = *(const short8v*)&Xf[((size_t)(m0t + wm * 4 + mi) * 8 + kt0) * 512 + l * 8];
#pragma unroll
      for (int ni = 0; ni < 2; ++ni)
        bfr[ni] = *(const short8v*)&Wf[((size_t)(z * 8 + kt0) * 16 + (n0 >> 4) + wn * 2 + ni) * 512 + l * 8];
#pragma unroll
      for (int mi = 0; mi < 4; ++mi)
#pragma unroll
        for (int ni = 0; ni < 2; ++ni)
          acc[mi][ni] = __builtin_amdgcn_mfma_f32_16x16x32_bf16(a[mi], bfr[ni], acc[mi][ni], 0, 0, 0);
    }

#pragma unroll
    for (int mi = 0; mi < 4; ++mi) {
#pragma unroll
      for (int ni = 0; ni < 2; ++ni) {
        const int col = n0 + wn * 32 + ni * 16 + lc;
        const int hh = col >> 5, d = col & 31;
#pragma unroll
        for (int r = 0; r < 4; ++r) {
          const int row = (m0t + wm * 4 + mi) * 16 + lg * 4 + r;
          const int bb = row >> 10, lr = row & (L_DIM - 1);
          const ushort_t bv = f2bf(acc[mi][ni][r]);
          if (z == 2) {
            Vf[(((size_t)(bb * H_DIM + hh) * 32 + (lr >> 5)) * 2 + (d >> 4)) * 512 +
               (((lr >> 3) & 3) * 16 + (d & 15)) * 8 + (lr & 7)] = bv;
          } else {
            ushort_t* of16 = (z == 0) ? Qf : Kf;
            of16[((size_t)((bb * H_DIM + hh) * 64 + (lr >> 4))) * 512 +
                 ((d >> 3) * 16 + (lr & 15)) * 8 + (d & 7)] = bv;
          }
        }
      }
    }
  } else {
    // ---- tk tile: exact decode of (b, qt, kt) from live-tile index ----
    const int lin = blk - 384;              // 0..4223
    const int b = lin / NTILES_TOT;
    const int t1 = lin - b * NTILES_TOT;    // 0..1055
    int m = (int)sqrtf((float)t1 + 1.0f);
    while (m * m + m > t1) --m;
    while ((m + 1) * (m + 1) + (m + 1) <= t1) ++m;
    const int rem = t1 - (m * m + m);
    int qt, kt;
    if (rem <= m) { qt = 2 * m; kt = rem; }
    else          { qt = 2 * m + 1; kt = rem - (m + 1); }

    const int q0 = qt << 4, k0 = kt << 5;
    if (tid < 16 * TD) {
      int i = tid >> 3, d = tid & 7;
      size_t base = (size_t)(b * L_DIM + q0 + i) * TD + d;
      ptq[i][d] = ptf[base]; qs[i][d] = sg[base]; qb[i][d] = bs[base];
    }
    {
      int j = tid >> 3, d = tid & 7;        // 32*8 = 256 exactly
      size_t base = (size_t)(b * L_DIM + k0 + j) * TD + d;
      ptk[j][d] = ptf[base]; ks[j][d] = sg[base]; kb[j][d] = bs[base];
    }
    if (tid < 16) trow[tid] = t_in[b * L_DIM + q0 + tid];
    if (tid < 32) tcol[tid] = t_in[b * L_DIM + k0 + tid];
    __syncthreads();
    float* dst = &tkbuf[(size_t)(b * NTILES_TOT + off_of(qt) + kt) * 512];
#pragma unroll
    for (int pp = 0; pp < 2; ++pp) {
      int idx = tid + (pp << 8);
      int lr2 = (idx >> 2) & 63;
      int r = idx & 3;
      int i = ((lr2 >> 4) << 2) | r;
      int j = ((idx >> 8) << 4) | (lr2 & 15);
      float td2 = trow[i] - tcol[j];
      td2 *= td2;
      float a = 0.f;
#pragma unroll
      for (int d = 0; d < TD; ++d) {
        float sqd = qs[i][d], skd = ks[j][d];
        float denom = sqd * sqd + skd * skd;
        float inv = __builtin_amdgcn_rcpf(denom);
        float ee = __expf(-td2 * inv);
        float le = __builtin_amdgcn_sqrtf(2.f * sqd * skd * inv);
        float dq = ptq[i][d] - ptk[j][d];
        float ce = __cosf(TWO_PI_F * dq);
        a += qb[i][d] * kb[j][d] * (le * ee * ce);
      }
      dst[idx] = a;
    }
  }
}

// ---------------------------------------------------------------------------
// Kernel 3: ATTENTION (x<16) + ROW-0 fixup (x==16), grid (17, 8, 4).
// Attention: 4 waves x 16 q-rows, zero barriers, frags straight from global
// bf16 buffers; LDS only for wave-private P transpose. Balanced qc mapping.
// Row0: softmax over ALL keys (uniform -10000 row), frag-buffer reads.
// ---------------------------------------------------------------------------
__global__ __launch_bounds__(256) void attn_row0_kernel(
    const ushort_t* __restrict__ Qf, const ushort_t* __restrict__ Kf,
    const ushort_t* __restrict__ Vf, const float* __restrict__ tkbuf,
    const int* __restrict__ imask, float* __restrict__ out) {
  __shared__ __align__(16) ushort_t lds_p[4][1024];  // attn: per-wave P (8 KB)
  __shared__ float p_s[L_DIM];                       // row0 (4 KB)
  __shared__ float qsh[D_DIM];
  __shared__ float red[8][33];
  __shared__ float rtmp[4];

  const int h = blockIdx.y;
  const int b = blockIdx.z;
  const int tid = threadIdx.x;
  const int fb = (b * H_DIM + h) * 64;   // frag-tile base (16-row tiles)
  const int vb = (b * H_DIM + h) * 32;   // V-group base (32-key groups)

  if (blockIdx.x == 16) {
    // ---------------- row-0 path ----------------
    if (tid < D_DIM)
      qsh[tid] = bf2f(Qf[(size_t)fb * 512 + (tid >> 3) * 128 + (tid & 7)]);
    __syncthreads();

    float lmax = -1e30f;
    for (int j = tid; j < L_DIM; j += 256) {
      int i = j & 15;
      float tkv = tkbuf[(size_t)(b * NTILES_TOT + off_of(j >> 4)) * 512 +
                        (((i >> 2) << 6) | (i & 3))];
      const ushort_t* kp = &Kf[(size_t)(fb + (j >> 4)) * 512 + (j & 15) * 8];
      float dot = 0.f;
#pragma unroll
      for (int o = 0; o < 4; ++o) {
        short8v kv = *(const short8v*)&kp[o * 128];
#pragma unroll
        for (int u = 0; u < 8; ++u) dot += qsh[o * 8 + u] * bf2f((ushort_t)kv[u]);
      }
      float sc = (dot + tkv) * SCALE;
      p_s[j] = sc;
      lmax = fmaxf(lmax, sc);
    }
#pragma unroll
    for (int o = 1; o < 64; o <<= 1) lmax = fmaxf(lmax, __shfl_xor(lmax, o));
    if ((tid & 63) == 0) rtmp[tid >> 6] = lmax;
    __syncthreads();
    const float bmax = fmaxf(fmaxf(rtmp[0], rtmp[1]), fmaxf(rtmp[2], rtmp[3]));
    __syncthreads();

    float lsumv = 0.f;
    for (int j = tid; j < L_DIM; j += 256) {
      float pv = __expf(p_s[j] - bmax);
      p_s[j] = pv;
      lsumv += pv;
    }
#pragma unroll
    for (int o = 1; o < 64; o <<= 1) lsumv += __shfl_xor(lsumv, o);
    if ((tid & 63) == 0) rtmp[tid >> 6] = lsumv;
    __syncthreads();
    const float bsum = rtmp[0] + rtmp[1] + rtmp[2] + rtmp[3];

    const int g = tid >> 5, d = tid & 31;
    float a = 0.f;
    for (int j = g * 128; j < g * 128 + 128; ++j) {
      float v = bf2f(Vf[(((size_t)(vb + (j >> 5))) * 2 + (d >> 4)) * 512 +
                        (((j >> 3) & 3) * 16 + (d & 15)) * 8 + (j & 7)]);
      a = fmaf(p_s[j], v, a);
    }
    red[g][d] = a;
    __syncthreads();
    if (tid < D_DIM) {
      float acc = 0.f;
#pragma unroll
      for (int gg = 0; gg < 8; ++gg) acc += red[gg][tid];
      float qabs = 0.f;
#pragma unroll
      for (int dd = 0; dd < D_DIM; ++dd) qabs += fabsf(qsh[dd]);
      const float qmv = qabs > 0.f ? 1.f : 0.f;
      out[((size_t)b * L_DIM) * 256 + h * D_DIM + tid] =
          acc * (1.0f / bsum) * qmv * (float)imask[b * L_DIM];
    }
    return;
  }

  // ---------------- attention path ----------------
  const int qc = (b >= 2) ? (int)blockIdx.x : 15 - (int)blockIdx.x;
  const int w = tid >> 6;
  const int l = tid & 63;
  const int lg = l >> 4;
  const int lc = l & 15;
  const int qbase = qc * 64 + w * 16;
  const int qt = qbase >> 4;

  short8v qfrag = *(const short8v*)&Qf[((size_t)(fb + qt)) * 512 + l * 8];
  float qabs_l = 0.f;
#pragma unroll
  for (int j = 0; j < 8; ++j) qabs_l += fabsf(bf2f((ushort_t)qfrag[j]));
  qabs_l += __shfl_xor(qabs_l, 16);
  qabs_l += __shfl_xor(qabs_l, 32);
  const float qm = (qabs_l > 0.f) ? 1.f : 0.f;

  f32x4 O0 = {0.f, 0.f, 0.f, 0.f};
  f32x4 O1 = {0.f, 0.f, 0.f, 0.f};
  float mrow[4] = {-1e30f, -1e30f, -1e30f, -1e30f};
  float lrow[4] = {0.f, 0.f, 0.f, 0.f};
  const float* tk_qt = &tkbuf[(size_t)(b * NTILES_TOT + off_of(qt)) * 512];
  ushort_t* Pw = lds_p[w];

  for (int kc = 0; kc <= qc; ++kc) {
    float s[4][4];
    const bool diag = (kc == qc);
#pragma unroll
    for (int kt = 0; kt < 4; ++kt) {
      short8v kfrag = *(const short8v*)&Kf[((size_t)(fb + kc * 4 + kt)) * 512 + l * 8];
      f32x4 z4 = {0.f, 0.f, 0.f, 0.f};
      f32x4 sv = __builtin_amdgcn_mfma_f32_16x16x32_bf16(qfrag, kfrag, z4, 0, 0, 0);
      float4 tk4 = *(const float4*)&tk_qt[(size_t)(kc * 2 + (kt >> 1)) * 512 + (kt & 1) * 256 + l * 4];
      float tka[4] = {tk4.x, tk4.y, tk4.z, tk4.w};
      const int col = kc * 64 + kt * 16 + lc;
#pragma unroll
      for (int r = 0; r < 4; ++r) {
        float val = (sv[r] + tka[r]) * SCALE;
        if (diag && col >= qbase + lg * 4 + r) val = -10000.0f;
        s[kt][r] = val;
      }
    }

#pragma unroll
    for (int r = 0; r < 4; ++r) {
      float tmax = fmaxf(fmaxf(s[0][r], s[1][r]), fmaxf(s[2][r], s[3][r]));
      tmax = fmaxf(tmax, __shfl_xor(tmax, 1));
      tmax = fmaxf(tmax, __shfl_xor(tmax, 2));
      tmax = fmaxf(tmax, __shfl_xor(tmax, 4));
      tmax = fmaxf(tmax, __shfl_xor(tmax, 8));
      float mnew = fmaxf(mrow[r], tmax);
      float cf = __expf(mrow[r] - mnew);
      mrow[r] = mnew;
      float p0 = __expf(s[0][r] - mnew);
      float p1 = __expf(s[1][r] - mnew);
      float p2 = __expf(s[2][r] - mnew);
      float p3 = __expf(s[3][r] - mnew);
      float psum = (p0 + p1) + (p2 + p3);
      psum += __shfl_xor(psum, 1);
      psum += __shfl_xor(psum, 2);
      psum += __shfl_xor(psum, 4);
      psum += __shfl_xor(psum, 8);
      lrow[r] = lrow[r] * cf + psum;
      O0[r] *= cf;
      O1[r] *= cf;
      const int pb = ((lc >> 3) << 7) + ((lg * 4 + r) << 3) + (lc & 7);
      Pw[pb] = f2bf(p0);
      Pw[pb + 256] = f2bf(p1);
      Pw[pb + 512] = f2bf(p2);
      Pw[pb + 768] = f2bf(p3);
    }

#pragma unroll
    for (int kh = 0; kh < 2; ++kh) {
      short8v pfrag = *(const short8v*)&Pw[(kh * 64 + l) * 8];
      const size_t vbase = ((size_t)(vb + kc * 2 + kh)) * 1024 + l * 8;
      short8v vf0 = *(const short8v*)&Vf[vbase];
      short8v vf1 = *(const short8v*)&Vf[vbase + 512];
      O0 = __builtin_amdgcn_mfma_f32_16x16x32_bf16(pfrag, vf0, O0, 0, 0, 0);
      O1 = __builtin_amdgcn_mfma_f32_16x16x32_bf16(pfrag, vf1, O1, 0, 0, 0);
    }
  }

#pragma unroll
  for (int r = 0; r < 4; ++r) {
    const int rr = lg * 4 + r;
    const int qrow = qbase + rr;
    float qmr = __shfl(qm, rr);
    float im = (float)imask[b * L_DIM + qrow];
    float scl = (1.f / lrow[r]) * qmr * im;
    if (qrow != 0) {
      float* op = &out[((size_t)(b * L_DIM + qrow)) * 256 + h * D_DIM];
      op[lc] = O0[r] * scl;
      op[16 + lc] = O1[r] * scl;
    }
  }
}

// ---------------------------------------------------------------------------
extern "C" void kernel_launch(void* const* d_in, const int* in_sizes, int n_in,
                              void* d_out, int out_size, void* d_ws, size_t ws_size,
                              hipStream_t stream) {
  (void)in_sizes; (void)n_in; (void)out_size; (void)ws_size;
  const float* query = (const float*)d_in[0];
  const float* input = (const float*)d_in[1];
  const int* imask = (const int*)d_in[2];
  const float* t_in = (const float*)d_in[3];
  const float* Wq = (const float*)d_in[5];
  const float* Wk = (const float*)d_in[6];
  const float* Wv = (const float*)d_in[7];
  const float* pW1 = (const float*)d_in[8],  *pb1 = (const float*)d_in[9];
  const float* pW2 = (const float*)d_in[10], *pb2 = (const float*)d_in[11];
  const float* sW1 = (const float*)d_in[12], *sb1 = (const float*)d_in[13];
  const float* sW2 = (const float*)d_in[14], *sb2 = (const float*)d_in[15];
  const float* bW1 = (const float*)d_in[16], *bb1 = (const float*)d_in[17];
  const float* bW2 = (const float*)d_in[18], *bb2 = (const float*)d_in[19];
  float* out = (float*)d_out;

  const int M = B_DIM * L_DIM;  // 4096
  char* p = (char*)d_ws;
  ushort_t* Qf = (ushort_t*)p;  p += (size_t)M * 256 * 2;   // 2 MB
  ushort_t* Kf = (ushort_t*)p;  p += (size_t)M * 256 * 2;
  ushort_t* Vf = (ushort_t*)p;  p += (size_t)M * 256 * 2;
  ushort_t* Xfq = (ushort_t*)p; p += (size_t)M * 256 * 2;
  ushort_t* Xfi = (ushort_t*)p; p += (size_t)M * 256 * 2;
  ushort_t* Wfb = (ushort_t*)p; p += (size_t)3 * 256 * 256 * 2;
  float* ptf = (float*)p;       p += (size_t)M * TD * 4;
  float* sg = (float*)p;        p += (size_t)M * TD * 4;
  float* bs = (float*)p;        p += (size_t)M * TD * 4;
  float* tkbuf = (float*)p;     // 4*1056*512*4 = 8.65 MB

  prep_kernel<<<1632, 256, 0, stream>>>(
      t_in, pW1, pb1, pW2, pb2, sW1, sb1, sW2, sb2, bW1, bb1, bW2, bb2,
      ptf, sg, bs, query, input, Xfq, Xfi, Wq, Wk, Wv, Wfb);
  work_kernel<<<384 + B_DIM * NTILES_TOT, 256, 0, stream>>>(
      Xfq, Xfi, Wfb, Qf, Kf, Vf, ptf, sg, bs, t_in, tkbuf);
  attn_row0_kernel<<<dim3(17, H_DIM, B_DIM), 256, 0, stream>>>(
      Qf, Kf, Vf, tkbuf, imask, out);
}